// Round 9
// baseline (156.444 us; speedup 1.0000x reference)
//
#include <hip/hip_runtime.h>

#define EPSLN 1e-5f
#define KMINC 9
#define SLI   10         // slices per (b,i), 8 rows each -> covers n <= 80

typedef _Float16 h2 __attribute__((ext_vector_type(2)));
typedef _Float16 h4 __attribute__((ext_vector_type(4)));

#if defined(__has_builtin)
#if __has_builtin(__builtin_amdgcn_fdot2)
#define FDOT2(a,b,c) __builtin_amdgcn_fdot2((a),(b),(c),false)
#endif
#endif
#ifndef FDOT2
#define FDOT2(a,b,c) ((c) + (float)(a)[0]*(float)(b)[0] + (float)(a)[1]*(float)(b)[1])
#endif

__device__ __forceinline__ h2 mk2(float a, float b){
  h2 v; v[0]=(_Float16)a; v[1]=(_Float16)b; return v;
}
__device__ __forceinline__ unsigned h2bits(h2 v){
  union { h2 h; unsigned u; } c; c.h = v; return c.u;
}
__device__ __forceinline__ h2 asH2(unsigned u){
  union { unsigned u; h2 h; } c; c.u = u; return c.h;
}

__device__ __forceinline__ float wred64(float v){
  #pragma unroll
  for (int m=1;m<64;m<<=1) v += __shfl_xor(v,m,64);
  return v;
}
__device__ __forceinline__ float wred32(float v){
  #pragma unroll
  for (int m=1;m<32;m<<=1) v += __shfl_xor(v,m,64);
  return v;
}

// ws word-offsets
#define WS_NODE   0            // 16384 f32
#define WS_CNT    16384        // 512 i32
#define WS_JLIST  16896        // 512*96 i32 -> ends 66048
#define WS_M0B    66048        // 512*16 f32 -> ends 74240
#define WS_PART   74240        // 512*SLI*28 f32 -> ends 217600
#define WS_PACKW  217600       // 3328 u32 weights + 192 Wc + 160 f32 consts -> ends 221280
#define WS_DONE   221280       // 512 i32

// packW layout (u32 words):
//  [0,2048)    GwP  = diag(g_pair)@We, q-blocked f16 pairs
//  [2048,2560) GwaP = diag(g_edge)@Wa, q-blocked
//  [2560,3328) W0P q-blocked
//  [3328,3520) WcP q-blocked
//  f32: [3520) waD[32], [3552) gw[32], [3584) bw[32], [3616) gwa[32], [3648) bwa[32]

// ---------------- Kernel P: msa-LN/attention/node + m0b + top-k mask + weight fold/pack ----------------
// grid = B*L (512), block = 512 (8 waves)
__global__ __launch_bounds__(512) void k_prep(
    const float* __restrict__ msa, const float* __restrict__ seq1hot,
    const float* __restrict__ xyz, const int* __restrict__ idxp,
    const int* __restrict__ topk,
    const float* __restrict__ g_msa, const float* __restrict__ b_msa,
    const float* __restrict__ g_pair, const float* __restrict__ b_pair,
    const float* __restrict__ Wq, const float* __restrict__ bq,
    const float* __restrict__ Wk, const float* __restrict__ bk,
    const float* __restrict__ Wx, const float* __restrict__ bx,
    const float* __restrict__ g_node, const float* __restrict__ b_node,
    const float* __restrict__ We, const float* __restrict__ be,
    const float* __restrict__ g_edge, const float* __restrict__ b_edge,
    const float* __restrict__ Wa, const float* __restrict__ ba,
    const float* __restrict__ W0, const float* __restrict__ b0,
    const float* __restrict__ Wc1, const float* __restrict__ Wc2,
    float* __restrict__ node, int* __restrict__ cnt, int* __restrict__ jlist,
    float* __restrict__ m0bG, unsigned* __restrict__ packW, int* __restrict__ done)
{
  const int bid = blockIdx.x;          // b*256 + l  (l == i)
  const int b = bid >> 8;
  const int tid = threadIdx.x;
  const int w = tid >> 6, lane = tid & 63;   // 8 waves

  __shared__ float mn[32][64];
  __shared__ float qS[64];
  __shared__ float scS[32];
  __shared__ float redS[8][64];
  __shared__ float ssumS[8];
  __shared__ float nodeS[32];
  __shared__ alignas(16) float Dv[256];
  __shared__ int   wsum[4];

  if (tid==0) done[bid] = 0;           // finish counter reset (visible to k_main at kernel boundary)

  // ---- block 0: LN-folded weight packing ----
  if (bid==0){
    for (int i=tid;i<2048;i+=512){
      int qb=i>>7, r7=i&127, t=r7>>2, i2=r7&3, q=4*qb+i2;
      packW[i] = h2bits(mk2(g_pair[2*q]*We[(2*q)*32+t], g_pair[2*q+1]*We[(2*q+1)*32+t]));
    }
    for (int i=tid;i<512; i+=512){
      int qb=i>>7, r7=i&127, t=r7>>2, i2=r7&3, q=4*qb+i2;
      packW[2048+i] = h2bits(mk2(g_edge[2*q]*Wa[(2*q)*32+t], g_edge[2*q+1]*Wa[(2*q+1)*32+t]));
    }
    for (int i=tid;i<768; i+=512){
      int qb=i>>6, r6=i&63, tc=r6>>2, i2=r6&3, q=4*qb+i2;
      packW[2560+i] = h2bits(mk2(W0[(2*q)*16+tc], W0[(2*q+1)*16+tc]));
    }
    if (tid<192){
      int qb=tid/48, r48=tid%48, tc=r48>>2, i2=r48&3, q=4*qb+i2;
      float lo = (tc<3)? Wc1[(2*q)*3+tc]   : Wc2[(2*q)*9+(tc-3)];
      float hi = (tc<3)? Wc1[(2*q+1)*3+tc] : Wc2[(2*q+1)*9+(tc-3)];
      packW[3328+tid] = h2bits(mk2(lo,hi));
    }
    if (tid<32){
      float* pf = (float*)packW;
      pf[3520+tid] = Wa[32*32+tid];                       // waD
      float gw=0.f, bw=0.f;
      for (int k=0;k<128;k++){
        gw += g_pair[k]*We[k*32+tid];
        bw += b_pair[k]*We[k*32+tid];
      }
      pf[3552+tid] = gw;
      pf[3584+tid] = bw + be[tid];
      float gwa=0.f, bwa=0.f;
      for (int c=0;c<32;c++){
        gwa += g_edge[c]*Wa[c*32+tid];
        bwa += b_edge[c]*Wa[c*32+tid];
      }
      pf[3616+tid] = gwa;
      pf[3648+tid] = bwa + ba[tid];
    }
  }

  // ---- msa LN: wave w rows w, w+8, w+16, w+24 ----
  const float gm = g_msa[lane], bm = b_msa[lane];
  for (int nn=w; nn<32; nn+=8){
    float x = msa[(size_t)(((b*32+nn)<<8)+(bid&255))*64 + lane];
    float s = wred64(x), s2 = wred64(x*x);
    float mu = s*(1.f/64.f);
    float var = s2*(1.f/64.f) - mu*mu;
    mn[nn][lane] = (x-mu)*rsqrtf(var+EPSLN)*gm + bm;
  }
  __syncthreads();
  {
    float p = (w==0)? bq[lane] : 0.f;
    for (int d=w*8; d<w*8+8; d++) p += mn[0][d]*Wq[d*64+lane];
    redS[w][lane] = p;
  }
  __syncthreads();
  if (w==0){
    float q = 0.f;
    #pragma unroll
    for (int k=0;k<8;k++) q += redS[k][lane];
    qS[lane] = q*0.125f;               // 1/sqrt(64)
  }
  __syncthreads();
  {
    float p = 0.f;
    for (int e=w*8; e<w*8+8; e++) p += Wk[lane*64+e]*qS[e];
    redS[w][lane] = p;
  }
  __syncthreads();
  float qk = 0.f;
  #pragma unroll
  for (int k=0;k<8;k++) qk += redS[k][lane];
  const float qb_ = wred64(qS[lane]*bk[lane]);
  for (int nn=w*4; nn<w*4+4; nn++){
    float p = wred64(mn[nn][lane]*qk);
    if (lane==0) scS[nn] = p + qb_;
  }
  __syncthreads();
  float mx = -1e30f;
  for (int nn=0; nn<32; nn++) mx = fmaxf(mx, scS[nn]);
  float ps=0.f, pm=0.f;
  for (int nn=w*4; nn<w*4+4; nn++){
    float e = expf(scS[nn]-mx);
    ps += e; pm += e*mn[nn][lane];
  }
  redS[w][lane] = pm;
  if (lane==0) ssumS[w] = ps;
  __syncthreads();
  if (w==0){
    float ssum = 0.f, acc = 0.f;
    #pragma unroll
    for (int k=0;k<8;k++){ ssum += ssumS[k]; acc += redS[k][lane]; }
    qS[lane] = acc / ssum;
  }
  __syncthreads();
  if (tid<32){
    float acc = bx[tid];
    for (int k=0;k<64;k++) acc += qS[k]*Wx[k*32+tid];
    const float* s1 = &seq1hot[bid*21];
    for (int k=0;k<21;k++) acc += s1[k]*Wx[(64+k)*32+tid];
    float s = wred32(acc), s2 = wred32(acc*acc);
    float mu = s*(1.f/32.f), var = s2*(1.f/32.f)-mu*mu;
    float v = (acc-mu)*rsqrtf(var+EPSLN)*g_node[tid] + b_node[tid];
    node[bid*32+tid] = v;
    nodeS[tid] = v;
  }
  __syncthreads();
  if (tid<16){
    float acc = b0[tid];
    for (int k=0;k<32;k++) acc += nodeS[k]*W0[(32+k)*16+tid];
    m0bG[bid*16+tid] = acc;
  }

  // --- Phase 2: distances, exact stable top-k rank, compaction (tid<256, thread=j) ---
  const bool act = tid < 256;
  const int i = bid & 255;
  const int j = tid;
  float D = 0.f;
  if (act){
    const float cax = xyz[(bid*3+1)*3+0];
    const float cay = xyz[(bid*3+1)*3+1];
    const float caz = xyz[(bid*3+1)*3+2];
    const int jb = (b<<8)+j;
    float dx = xyz[(jb*3+1)*3+0]-cax;
    float dy = xyz[(jb*3+1)*3+1]-cay;
    float dz = xyz[(jb*3+1)*3+2]-caz;
    D = sqrtf(dx*dx+dy*dy+dz*dz) + (i==j ? 999.9f : 0.f);
  }
  __syncthreads();
  if (act) Dv[j] = D;
  __syncthreads();
  if (act){
    int rank = 0;
    for (int j2=0;j2<256;j2+=4){
      const float4 dv = *(const float4*)&Dv[j2];
      rank += (dv.x < D || (dv.x == D && (j2+0) < j)) ? 1 : 0;
      rank += (dv.y < D || (dv.y == D && (j2+1) < j)) ? 1 : 0;
      rank += (dv.z < D || (dv.z == D && (j2+2) < j)) ? 1 : 0;
      rank += (dv.w < D || (dv.w == D && (j2+3) < j)) ? 1 : 0;
    }
    int K = topk[0];
    if (K<=0 || K>256){
      float f = ((const float*)topk)[0];
      K = (f>=1.f && f<=256.f) ? (int)f : 64;
    }
    const int jb = (b<<8)+j;
    const int sep = abs(idxp[jb] - idxp[bid]);
    const bool m = (rank < K) || (i!=j && sep < KMINC);
    unsigned long long bal = __ballot(m);
    const int l6 = j & 63, wv = j >> 6;
    const int pre = __popcll(bal & ((1ull<<l6)-1ull));
    if (l6==0) wsum[wv] = __popcll(bal);
    __syncthreads();
    int off = 0;
    for (int w2=0;w2<wv;w2++) off += wsum[w2];
    if (m) jlist[bid*96 + off + pre] = j;
    if (j==0) cnt[bid] = wsum[0]+wsum[1]+wsum[2]+wsum[3];
  } else {
    __syncthreads();
  }
}

// ---------------- Kernel C: wave-per-slice pipeline, LN-folded GEMVs, fused finisher ----------------
// grid = 512*SLI/4 (1280), block = 256 = 4 independent waves; wave = one 8-row slice.
// LN scales folded into packed weights: raw f16 operands go to LDS straight after the
// global load (no reduce in the staging path); rs/mu fold in at GEMV end (3 FMA).
// Last-arriving wave per item (done counter) performs the k_fin reduction (fixed slice
// order -> deterministic).
__global__ __launch_bounds__(256) void k_main(
    const float* __restrict__ pair, const float* __restrict__ xyz,
    const float* __restrict__ node, const int* __restrict__ cnt,
    const int* __restrict__ jlist, const float* __restrict__ m0bG,
    const unsigned* __restrict__ packW, float* __restrict__ part,
    int* __restrict__ done, float* __restrict__ out)
{
  const int tid = threadIdx.x;
  const int w  = tid >> 6;          // wave 0..3
  const int wl = tid & 63;          // lane in wave
  const int r  = (tid >> 5) & 1;    // group in wave
  const int t  = tid & 31;          // lane in group

  __shared__ alignas(16) unsigned GwL[2048];        // 8 KB
  __shared__ alignas(16) unsigned GwaL[512];        // 2 KB
  __shared__ alignas(16) unsigned W0L[768];         // 3 KB
  __shared__ alignas(16) unsigned WcL[192];         // 768 B
  __shared__ float waDS[32], gwS[32], bwS[32], gwaS[32], bwaS[32];
  __shared__ alignas(16) _Float16 pnH[32][128];     // 8 KB raw pair rows f16
  __shared__ alignas(16) _Float16 eH [32][32];      // 2 KB raw edge (pre-LN) f16
  __shared__ alignas(16) _Float16 aH [32][32];      // 2 KB
  __shared__ alignas(16) _Float16 ndH[32][32];      // 2 KB
  __shared__ float cS[32*12];
  __shared__ float xjS[32][9];
  __shared__ float geoS[32][4];

  for (int i2=tid;i2<2048;i2+=256) GwL[i2] = packW[i2];
  for (int i2=tid;i2<512; i2+=256) GwaL[i2] = packW[2048+i2];
  for (int i2=tid;i2<768; i2+=256) W0L[i2] = packW[2560+i2];
  if (tid<192) WcL[tid] = packW[3328+tid];
  if (tid<32){
    const float* pf = (const float*)packW;
    waDS[tid]=pf[3520+tid]; gwS[tid]=pf[3552+tid]; bwS[tid]=pf[3584+tid];
    gwaS[tid]=pf[3616+tid]; bwaS[tid]=pf[3648+tid];
  }
  __syncthreads();        // the ONLY block-wide barrier

  const int s    = blockIdx.x*4 + w;   // slice id
  const int item = s / SLI;            // (b,i)
  const int sl   = s - item*SLI;
  const int b    = item >> 8;
  const int n    = cnt[item];
  const int row0 = sl*8;
  const int wrow = w*8;

  float stA = 0.f;
  float ofA = 0.f;

  if (row0 < n){
    const float cax = xyz[(item*3+1)*3+0];
    const float cay = xyz[(item*3+1)*3+1];
    const float caz = xyz[(item*3+1)*3+2];
    bool vals[4];
    float rsA[4], rmA[4];
    // ---- stage 4 rows per group: raw p -> pnH immediately; reductions off the write path ----
    #pragma unroll
    for (int jc=0;jc<4;jc++){
      const int slot = row0 + r*4 + jc;
      vals[jc] = slot < n;
      const int jj = vals[jc] ? jlist[item*96 + slot] : 0;
      const int row = wrow + r*4 + jc;
      const float* prow = &pair[((long)item*256 + jj)*128];
      const float4 pv4 = *(const float4*)&prow[4*t];
      h4 o;
      o[0]=(_Float16)pv4.x; o[1]=(_Float16)pv4.y;
      o[2]=(_Float16)pv4.z; o[3]=(_Float16)pv4.w;
      *(h4*)&pnH[row][4*t] = o;
      const int jb=(b<<8)+jj;
      ndH[row][t] = (_Float16)node[jb*32+t];
      if (t<9) xjS[row][t] = xyz[(size_t)jb*9 + t];
      if (t==0){
        float jx = xyz[(size_t)jb*9+3]-cax;
        float jy = xyz[(size_t)jb*9+4]-cay;
        float jz = xyz[(size_t)jb*9+5]-caz;
        geoS[row][0]=jx; geoS[row][1]=jy; geoS[row][2]=jz;
        geoS[row][3]=sqrtf(jx*jx+jy*jy+jz*jz);
      }
      float sm  = wred32(pv4.x+pv4.y+pv4.z+pv4.w);
      float sm2 = wred32(pv4.x*pv4.x+pv4.y*pv4.y+pv4.z*pv4.z+pv4.w*pv4.w);
      float mu = sm*(1.f/128.f);
      float var = sm2*(1.f/128.f)-mu*mu;
      float rs = rsqrtf(var+EPSLN);
      rsA[jc]=rs; rmA[jc]=rs*mu;
    }
    // ---- edge GEMV over raw p with folded weights; LN fold at the end ----
    float ea0[4], ea1[4];
    #pragma unroll
    for (int jc=0;jc<4;jc++){ ea0[jc]=0.f; ea1[jc]=0.f; }
    for (int qb=0; qb<16; ++qb){
      const uint4 wv = *(const uint4*)&GwL[qb*128 + t*4];
      #pragma unroll
      for (int jc=0;jc<4;jc++){
        const uint4 pv = *(const uint4*)&pnH[wrow + r*4 + jc][8*qb];
        ea0[jc]=FDOT2(asH2(wv.y), asH2(pv.y), FDOT2(asH2(wv.x), asH2(pv.x), ea0[jc]));
        ea1[jc]=FDOT2(asH2(wv.w), asH2(pv.w), FDOT2(asH2(wv.z), asH2(pv.z), ea1[jc]));
      }
    }
    // e (pre-LN edge incl. bias) -> eH immediately; its LN reductions overlap a-GEMV
    float rs2A[4], rm2A[4];
    #pragma unroll
    for (int jc=0;jc<4;jc++){
      float e = rsA[jc]*(ea0[jc]+ea1[jc]) - rmA[jc]*gwS[t] + bwS[t];
      eH[wrow + r*4 + jc][t] = (_Float16)e;
      float sm=wred32(e), sm2=wred32(e*e);
      float mu=sm*(1.f/32.f), var=sm2*(1.f/32.f)-mu*mu;
      float rs2=rsqrtf(var+EPSLN);
      rs2A[jc]=rs2; rm2A[jc]=rs2*mu;
    }
    // ---- a = relu(rs2*(e·Gwa) − rs2*mu2*gwa + bwa + dist*waD) ----
    float av[4];
    #pragma unroll
    for (int jc=0;jc<4;jc++) av[jc]=0.f;
    for (int qb=0; qb<4; ++qb){
      const uint4 wv = *(const uint4*)&GwaL[qb*128 + t*4];
      #pragma unroll
      for (int jc=0;jc<4;jc++){
        const uint4 ev = *(const uint4*)&eH[wrow + r*4 + jc][8*qb];
        av[jc]=FDOT2(asH2(wv.w), asH2(ev.w), FDOT2(asH2(wv.z), asH2(ev.z),
                FDOT2(asH2(wv.y), asH2(ev.y), FDOT2(asH2(wv.x), asH2(ev.x), av[jc]))));
      }
    }
    #pragma unroll
    for (int jc=0;jc<4;jc++){
      float a = rs2A[jc]*av[jc] - rm2A[jc]*gwaS[t] + bwaS[t]
              + geoS[wrow + r*4 + jc][3]*waDS[t];
      aH[wrow + r*4 + jc][t]=(_Float16)fmaxf(a,0.f);
    }
    // ---- m0: a-part lanes t<16 (W0 blocks 0..3), node-part t>=16 (blocks 8..11) ----
    {
      const int half = t>>4, tc = t&15;
      const int wb = half ? 8 : 0;
      const float m0b = half ? 0.f : m0bG[item*16+tc];
      float m0v[4];
      #pragma unroll
      for (int jc=0;jc<4;jc++) m0v[jc]=m0b;
      for (int qb=0;qb<4;++qb){
        const uint4 wv = *(const uint4*)&W0L[(wb+qb)*64 + tc*4];
        #pragma unroll
        for (int jc=0;jc<4;jc++){
          const _Float16* opb = half ? &ndH[wrow + r*4 + jc][0] : &aH[wrow + r*4 + jc][0];
          const uint4 ov = *(const uint4*)&opb[8*qb];
          m0v[jc]=FDOT2(asH2(wv.w), asH2(ov.w), FDOT2(asH2(wv.z), asH2(ov.z),
                   FDOT2(asH2(wv.y), asH2(ov.y), FDOT2(asH2(wv.x), asH2(ov.x), m0v[jc]))));
        }
      }
      #pragma unroll
      for (int jc=0;jc<4;jc++){
        float tot = m0v[jc] + __shfl_xor(m0v[jc], 16);
        if (t<16 && vals[jc]) stA += fmaxf(tot, 0.f);
      }
    }
    // ---- c1/c2 from a ----
    {
      const bool up = (t>=12 && t<24);
      const int tc12 = up ? t-12 : (t<12 ? t : 0);
      const int wb = up ? 2 : 0;
      const int koff = up ? 16 : 0;
      float cv[4]={0.f,0.f,0.f,0.f};
      for (int qb=0;qb<2;++qb){
        const uint4 wv = *(const uint4*)&WcL[(wb+qb)*48 + tc12*4];
        #pragma unroll
        for (int jc=0;jc<4;jc++){
          const uint4 av2 = *(const uint4*)&aH[wrow + r*4 + jc][koff + 8*qb];
          cv[jc]=FDOT2(asH2(wv.w), asH2(av2.w), FDOT2(asH2(wv.z), asH2(av2.z),
                  FDOT2(asH2(wv.y), asH2(av2.y), FDOT2(asH2(wv.x), asH2(av2.x), cv[jc]))));
        }
      }
      #pragma unroll
      for (int jc=0;jc<4;jc++){
        const int src = (t<12) ? t+12 : (up ? t-12 : t);
        float other = __shfl(cv[jc], src, 32);
        if (t<12) cS[(wrow + r*4 + jc)*12+t] = cv[jc]+other;
      }
    }
    // ---- offset accumulation (t<9) ----
    if (t<9){
      const int o=t/3, x=t-o*3;
      #pragma unroll
      for (int jc=0;jc<4;jc++){
        if (!vals[jc]) continue;
        const int row = wrow + r*4 + jc;
        const float dj = geoS[row][3];
        const float dh = geoS[row][x]/(dj+1e-8f);
        const float* cr = &cS[row*12];
        float val = cr[o]*dh;
        const float caxj = xjS[row][3+x];
        #pragma unroll
        for (int c=0;c<3;c++){
          val += cr[3+o*3+c]*(xjS[row][c*3+x]-caxj);
        }
        ofA += val;
      }
    }
  }

  // ---- write this slice's partial ----
  stA += __shfl_xor(stA, 32);
  ofA += __shfl_xor(ofA, 32);
  if (wl < 16) part[s*28 + wl] = stA;
  if (wl < 9)  part[s*28 + 16 + wl] = ofA;

  // ---- fused finisher: last wave of this item reduces all SLI partials ----
  __threadfence();
  int old = 0;
  if (wl==0) old = atomicAdd(&done[item], 1);
  old = __shfl(old, 0, 64);
  if (old == SLI-1){
    __threadfence();
    const float invd = 1.f/fmaxf((float)n,1.f);
    float sst=0.f, sof=0.f;
    #pragma unroll
    for (int k2=0;k2<SLI;k2++){
      const float* pp = &part[(item*SLI+k2)*28];
      if (wl<16) sst += pp[wl];
      if (wl<9)  sof += pp[16+wl];
    }
    if (wl<16) out[4608 + item*16 + wl] = sst*invd;     // state
    const float off = sof*invd;                          // off[wl] for wl<9
    const int x = wl - (wl/3)*3;                         // wl%3
    const float offca = __shfl(off, 3+x, 64);            // off[3+x]
    if (wl<9){
      const float cac = xyz[(item*3+1)*3 + x];
      const float CA = cac + offca;
      const int o = wl/3;
      out[item*9 + wl] = (o==1)? CA : (CA + off);        // xyz_new
    }
  }
}

extern "C" void kernel_launch(void* const* d_in, const int* in_sizes, int n_in,
                              void* d_out, int out_size, void* d_ws, size_t ws_size,
                              hipStream_t stream)
{
  const float* msa     = (const float*)d_in[0];
  const float* pair    = (const float*)d_in[1];
  const float* xyz     = (const float*)d_in[2];
  const float* seq1hot = (const float*)d_in[3];
  const float* g_msa   = (const float*)d_in[4];
  const float* b_msa   = (const float*)d_in[5];
  const float* g_pair  = (const float*)d_in[6];
  const float* b_pair  = (const float*)d_in[7];
  const float* Wq      = (const float*)d_in[8];
  const float* bq      = (const float*)d_in[9];
  const float* Wk      = (const float*)d_in[10];
  const float* bk      = (const float*)d_in[11];
  const float* Wx      = (const float*)d_in[12];
  const float* bx      = (const float*)d_in[13];
  const float* g_node  = (const float*)d_in[14];
  const float* b_node  = (const float*)d_in[15];
  const float* We      = (const float*)d_in[16];
  const float* be      = (const float*)d_in[17];
  const float* g_edge  = (const float*)d_in[18];
  const float* b_edge  = (const float*)d_in[19];
  const float* Wa      = (const float*)d_in[20];
  const float* ba      = (const float*)d_in[21];
  const float* W0      = (const float*)d_in[22];
  const float* b0      = (const float*)d_in[23];
  const float* Wc1     = (const float*)d_in[24];
  const float* Wc2     = (const float*)d_in[25];
  const int*   idx     = (const int*)d_in[26];
  const int*   topk    = (const int*)d_in[27];
  float* out = (float*)d_out;

  float* wsf = (float*)d_ws;
  float*    node  = wsf + WS_NODE;
  int*      cnt   = (int*)(wsf + WS_CNT);
  int*      jlist = (int*)(wsf + WS_JLIST);
  float*    m0bG  = wsf + WS_M0B;
  float*    partb = wsf + WS_PART;
  unsigned* packW = (unsigned*)(wsf + WS_PACKW);
  int*      done  = (int*)(wsf + WS_DONE);

  k_prep<<<512, 512, 0, stream>>>(msa, seq1hot, xyz, idx, topk, g_msa, b_msa,
                                  g_pair, b_pair, Wq, bq, Wk, bk, Wx, bx,
                                  g_node, b_node, We, be, g_edge, b_edge,
                                  Wa, ba, W0, b0, Wc1, Wc2,
                                  node, cnt, jlist, m0bG, packW, done);
  k_main<<<512*SLI/4, 256, 0, stream>>>(pair, xyz, node, cnt, jlist, m0bG,
                                        packW, partb, done, out);
}

// Round 10
// 50.803 us; speedup vs baseline: 3.0794x; 3.0794x over previous
//
#include <hip/hip_runtime.h>

#define EPSLN 1e-5f
#define KMINC 9
#define SLI   10         // slices per (b,i), 8 rows each -> covers n <= 80

typedef _Float16 h2 __attribute__((ext_vector_type(2)));
typedef _Float16 h4 __attribute__((ext_vector_type(4)));

#if defined(__has_builtin)
#if __has_builtin(__builtin_amdgcn_fdot2)
#define FDOT2(a,b,c) __builtin_amdgcn_fdot2((a),(b),(c),false)
#endif
#endif
#ifndef FDOT2
#define FDOT2(a,b,c) ((c) + (float)(a)[0]*(float)(b)[0] + (float)(a)[1]*(float)(b)[1])
#endif

__device__ __forceinline__ h2 mk2(float a, float b){
  h2 v; v[0]=(_Float16)a; v[1]=(_Float16)b; return v;
}
__device__ __forceinline__ unsigned h2bits(h2 v){
  union { h2 h; unsigned u; } c; c.h = v; return c.u;
}
__device__ __forceinline__ h2 asH2(unsigned u){
  union { unsigned u; h2 h; } c; c.u = u; return c.h;
}

__device__ __forceinline__ float wred64(float v){
  #pragma unroll
  for (int m=1;m<64;m<<=1) v += __shfl_xor(v,m,64);
  return v;
}
__device__ __forceinline__ float wred32(float v){
  #pragma unroll
  for (int m=1;m<32;m<<=1) v += __shfl_xor(v,m,64);
  return v;
}

// ws word-offsets
#define WS_NODE   0            // 16384 f32
#define WS_CNT    16384        // 512 i32
#define WS_JLIST  16896        // 512*96 i32 -> ends 66048
#define WS_M0B    66048        // 512*16 f32 -> ends 74240
#define WS_PART   74240        // 512*SLI*28 f32 -> ends 217600
#define WS_PACKW  217600       // 3520 u32 weights + 160 f32 consts

// packW layout (u32 words):
//  [0,2048)    GwP  = diag(g_pair)@We, q-blocked f16 pairs
//  [2048,2560) GwaP = diag(g_edge)@Wa, q-blocked
//  [2560,3328) W0P q-blocked
//  [3328,3520) WcP q-blocked
//  f32: [3520) waD[32], [3552) gw[32], [3584) bw[32], [3616) gwa[32], [3648) bwa[32]

// ---------------- Kernel P: msa-LN/attention/node + m0b + top-k mask + weight fold/pack ----------------
// grid = B*L (512), block = 512 (8 waves)
__global__ __launch_bounds__(512) void k_prep(
    const float* __restrict__ msa, const float* __restrict__ seq1hot,
    const float* __restrict__ xyz, const int* __restrict__ idxp,
    const int* __restrict__ topk,
    const float* __restrict__ g_msa, const float* __restrict__ b_msa,
    const float* __restrict__ g_pair, const float* __restrict__ b_pair,
    const float* __restrict__ Wq, const float* __restrict__ bq,
    const float* __restrict__ Wk, const float* __restrict__ bk,
    const float* __restrict__ Wx, const float* __restrict__ bx,
    const float* __restrict__ g_node, const float* __restrict__ b_node,
    const float* __restrict__ We, const float* __restrict__ be,
    const float* __restrict__ g_edge, const float* __restrict__ b_edge,
    const float* __restrict__ Wa, const float* __restrict__ ba,
    const float* __restrict__ W0, const float* __restrict__ b0,
    const float* __restrict__ Wc1, const float* __restrict__ Wc2,
    float* __restrict__ node, int* __restrict__ cnt, int* __restrict__ jlist,
    float* __restrict__ m0bG, unsigned* __restrict__ packW)
{
  const int bid = blockIdx.x;          // b*256 + l  (l == i)
  const int b = bid >> 8;
  const int tid = threadIdx.x;
  const int w = tid >> 6, lane = tid & 63;   // 8 waves

  __shared__ float mn[32][64];
  __shared__ float qS[64];
  __shared__ float scS[32];
  __shared__ float redS[8][64];
  __shared__ float ssumS[8];
  __shared__ float nodeS[32];
  __shared__ alignas(16) float Dv[256];
  __shared__ int   wsum[4];

  // ---- block 0: LN-folded weight packing ----
  if (bid==0){
    for (int i=tid;i<2048;i+=512){
      int qb=i>>7, r7=i&127, t=r7>>2, i2=r7&3, q=4*qb+i2;
      packW[i] = h2bits(mk2(g_pair[2*q]*We[(2*q)*32+t], g_pair[2*q+1]*We[(2*q+1)*32+t]));
    }
    for (int i=tid;i<512; i+=512){
      int qb=i>>7, r7=i&127, t=r7>>2, i2=r7&3, q=4*qb+i2;
      packW[2048+i] = h2bits(mk2(g_edge[2*q]*Wa[(2*q)*32+t], g_edge[2*q+1]*Wa[(2*q+1)*32+t]));
    }
    for (int i=tid;i<768; i+=512){
      int qb=i>>6, r6=i&63, tc=r6>>2, i2=r6&3, q=4*qb+i2;
      packW[2560+i] = h2bits(mk2(W0[(2*q)*16+tc], W0[(2*q+1)*16+tc]));
    }
    if (tid<192){
      int qb=tid/48, r48=tid%48, tc=r48>>2, i2=r48&3, q=4*qb+i2;
      float lo = (tc<3)? Wc1[(2*q)*3+tc]   : Wc2[(2*q)*9+(tc-3)];
      float hi = (tc<3)? Wc1[(2*q+1)*3+tc] : Wc2[(2*q+1)*9+(tc-3)];
      packW[3328+tid] = h2bits(mk2(lo,hi));
    }
    if (tid<32){
      float* pf = (float*)packW;
      pf[3520+tid] = Wa[32*32+tid];                       // waD
      float gw=0.f, bw=0.f;
      for (int k=0;k<128;k++){
        gw += g_pair[k]*We[k*32+tid];
        bw += b_pair[k]*We[k*32+tid];
      }
      pf[3552+tid] = gw;
      pf[3584+tid] = bw + be[tid];
      float gwa=0.f, bwa=0.f;
      for (int c=0;c<32;c++){
        gwa += g_edge[c]*Wa[c*32+tid];
        bwa += b_edge[c]*Wa[c*32+tid];
      }
      pf[3616+tid] = gwa;
      pf[3648+tid] = bwa + ba[tid];
    }
  }

  // ---- msa LN: wave w rows w, w+8, w+16, w+24 ----
  const float gm = g_msa[lane], bm = b_msa[lane];
  for (int nn=w; nn<32; nn+=8){
    float x = msa[(size_t)(((b*32+nn)<<8)+(bid&255))*64 + lane];
    float s = wred64(x), s2 = wred64(x*x);
    float mu = s*(1.f/64.f);
    float var = s2*(1.f/64.f) - mu*mu;
    mn[nn][lane] = (x-mu)*rsqrtf(var+EPSLN)*gm + bm;
  }
  __syncthreads();
  {
    float p = (w==0)? bq[lane] : 0.f;
    for (int d=w*8; d<w*8+8; d++) p += mn[0][d]*Wq[d*64+lane];
    redS[w][lane] = p;
  }
  __syncthreads();
  if (w==0){
    float q = 0.f;
    #pragma unroll
    for (int k=0;k<8;k++) q += redS[k][lane];
    qS[lane] = q*0.125f;               // 1/sqrt(64)
  }
  __syncthreads();
  {
    float p = 0.f;
    for (int e=w*8; e<w*8+8; e++) p += Wk[lane*64+e]*qS[e];
    redS[w][lane] = p;
  }
  __syncthreads();
  float qk = 0.f;
  #pragma unroll
  for (int k=0;k<8;k++) qk += redS[k][lane];
  const float qb_ = wred64(qS[lane]*bk[lane]);
  for (int nn=w*4; nn<w*4+4; nn++){
    float p = wred64(mn[nn][lane]*qk);
    if (lane==0) scS[nn] = p + qb_;
  }
  __syncthreads();
  float mx = -1e30f;
  for (int nn=0; nn<32; nn++) mx = fmaxf(mx, scS[nn]);
  float ps=0.f, pm=0.f;
  for (int nn=w*4; nn<w*4+4; nn++){
    float e = expf(scS[nn]-mx);
    ps += e; pm += e*mn[nn][lane];
  }
  redS[w][lane] = pm;
  if (lane==0) ssumS[w] = ps;
  __syncthreads();
  if (w==0){
    float ssum = 0.f, acc = 0.f;
    #pragma unroll
    for (int k=0;k<8;k++){ ssum += ssumS[k]; acc += redS[k][lane]; }
    qS[lane] = acc / ssum;
  }
  __syncthreads();
  if (tid<32){
    float acc = bx[tid];
    for (int k=0;k<64;k++) acc += qS[k]*Wx[k*32+tid];
    const float* s1 = &seq1hot[bid*21];
    for (int k=0;k<21;k++) acc += s1[k]*Wx[(64+k)*32+tid];
    float s = wred32(acc), s2 = wred32(acc*acc);
    float mu = s*(1.f/32.f), var = s2*(1.f/32.f)-mu*mu;
    float v = (acc-mu)*rsqrtf(var+EPSLN)*g_node[tid] + b_node[tid];
    node[bid*32+tid] = v;
    nodeS[tid] = v;
  }
  __syncthreads();
  if (tid<16){
    float acc = b0[tid];
    for (int k=0;k<32;k++) acc += nodeS[k]*W0[(32+k)*16+tid];
    m0bG[bid*16+tid] = acc;
  }

  // --- Phase 2: distances, exact stable top-k rank, compaction (tid<256, thread=j) ---
  const bool act = tid < 256;
  const int i = bid & 255;
  const int j = tid;
  float D = 0.f;
  if (act){
    const float cax = xyz[(bid*3+1)*3+0];
    const float cay = xyz[(bid*3+1)*3+1];
    const float caz = xyz[(bid*3+1)*3+2];
    const int jb = (b<<8)+j;
    float dx = xyz[(jb*3+1)*3+0]-cax;
    float dy = xyz[(jb*3+1)*3+1]-cay;
    float dz = xyz[(jb*3+1)*3+2]-caz;
    D = sqrtf(dx*dx+dy*dy+dz*dz) + (i==j ? 999.9f : 0.f);
  }
  __syncthreads();
  if (act) Dv[j] = D;
  __syncthreads();
  if (act){
    int rank = 0;
    for (int j2=0;j2<256;j2+=4){
      const float4 dv = *(const float4*)&Dv[j2];
      rank += (dv.x < D || (dv.x == D && (j2+0) < j)) ? 1 : 0;
      rank += (dv.y < D || (dv.y == D && (j2+1) < j)) ? 1 : 0;
      rank += (dv.z < D || (dv.z == D && (j2+2) < j)) ? 1 : 0;
      rank += (dv.w < D || (dv.w == D && (j2+3) < j)) ? 1 : 0;
    }
    int K = topk[0];
    if (K<=0 || K>256){
      float f = ((const float*)topk)[0];
      K = (f>=1.f && f<=256.f) ? (int)f : 64;
    }
    const int jb = (b<<8)+j;
    const int sep = abs(idxp[jb] - idxp[bid]);
    const bool m = (rank < K) || (i!=j && sep < KMINC);
    unsigned long long bal = __ballot(m);
    const int l6 = j & 63, wv = j >> 6;
    const int pre = __popcll(bal & ((1ull<<l6)-1ull));
    if (l6==0) wsum[wv] = __popcll(bal);
    __syncthreads();
    int off = 0;
    for (int w2=0;w2<wv;w2++) off += wsum[w2];
    if (m) jlist[bid*96 + off + pre] = j;
    if (j==0) cnt[bid] = wsum[0]+wsum[1]+wsum[2]+wsum[3];
  } else {
    __syncthreads();
  }
}

// ---------------- Kernel C: wave-per-slice pipeline, LN-folded GEMVs ----------------
// grid = 512*SLI/4 (1280), block = 256 = 4 independent waves; wave = one 8-row slice.
// LN scales folded into packed weights (k_prep): raw f16 operands go to LDS straight
// after the global load; rs/mu fold in at GEMV end (3 FMA). No fences/atomics —
// cross-block combine is the separate k_fin launch (r9 lesson: device-scope fence
// per wave costs ~3x the whole kernel).
__global__ __launch_bounds__(256) void k_main(
    const float* __restrict__ pair, const float* __restrict__ xyz,
    const float* __restrict__ node, const int* __restrict__ cnt,
    const int* __restrict__ jlist, const float* __restrict__ m0bG,
    const unsigned* __restrict__ packW, float* __restrict__ part)
{
  const int tid = threadIdx.x;
  const int w  = tid >> 6;          // wave 0..3
  const int wl = tid & 63;          // lane in wave
  const int r  = (tid >> 5) & 1;    // group in wave
  const int t  = tid & 31;          // lane in group

  __shared__ alignas(16) unsigned GwL[2048];        // 8 KB
  __shared__ alignas(16) unsigned GwaL[512];        // 2 KB
  __shared__ alignas(16) unsigned W0L[768];         // 3 KB
  __shared__ alignas(16) unsigned WcL[192];         // 768 B
  __shared__ float waDS[32], gwS[32], bwS[32], gwaS[32], bwaS[32];
  __shared__ alignas(16) _Float16 pnH[32][128];     // 8 KB raw pair rows f16
  __shared__ alignas(16) _Float16 eH [32][32];      // 2 KB raw edge (pre-LN-apply) f16
  __shared__ alignas(16) _Float16 aH [32][32];      // 2 KB
  __shared__ alignas(16) _Float16 ndH[32][32];      // 2 KB
  __shared__ float cS[32*12];
  __shared__ float xjS[32][9];
  __shared__ float geoS[32][4];

  for (int i2=tid;i2<2048;i2+=256) GwL[i2] = packW[i2];
  for (int i2=tid;i2<512; i2+=256) GwaL[i2] = packW[2048+i2];
  for (int i2=tid;i2<768; i2+=256) W0L[i2] = packW[2560+i2];
  if (tid<192) WcL[tid] = packW[3328+tid];
  if (tid<32){
    const float* pf = (const float*)packW;
    waDS[tid]=pf[3520+tid]; gwS[tid]=pf[3552+tid]; bwS[tid]=pf[3584+tid];
    gwaS[tid]=pf[3616+tid]; bwaS[tid]=pf[3648+tid];
  }
  __syncthreads();        // the ONLY block-wide barrier

  const int s    = blockIdx.x*4 + w;   // slice id
  const int item = s / SLI;            // (b,i)
  const int sl   = s - item*SLI;
  const int b    = item >> 8;
  const int n    = cnt[item];
  const int row0 = sl*8;
  const int wrow = w*8;

  float stA = 0.f;
  float ofA = 0.f;

  if (row0 < n){
    const float cax = xyz[(item*3+1)*3+0];
    const float cay = xyz[(item*3+1)*3+1];
    const float caz = xyz[(item*3+1)*3+2];
    bool vals[4];
    float rsA[4], rmA[4];
    // ---- stage 4 rows per group: raw p -> pnH immediately; reductions off the write path ----
    #pragma unroll
    for (int jc=0;jc<4;jc++){
      const int slot = row0 + r*4 + jc;
      vals[jc] = slot < n;
      const int jj = vals[jc] ? jlist[item*96 + slot] : 0;
      const int row = wrow + r*4 + jc;
      const float* prow = &pair[((long)item*256 + jj)*128];
      const float4 pv4 = *(const float4*)&prow[4*t];
      h4 o;
      o[0]=(_Float16)pv4.x; o[1]=(_Float16)pv4.y;
      o[2]=(_Float16)pv4.z; o[3]=(_Float16)pv4.w;
      *(h4*)&pnH[row][4*t] = o;
      const int jb=(b<<8)+jj;
      ndH[row][t] = (_Float16)node[jb*32+t];
      if (t<9) xjS[row][t] = xyz[(size_t)jb*9 + t];
      if (t==0){
        float jx = xyz[(size_t)jb*9+3]-cax;
        float jy = xyz[(size_t)jb*9+4]-cay;
        float jz = xyz[(size_t)jb*9+5]-caz;
        geoS[row][0]=jx; geoS[row][1]=jy; geoS[row][2]=jz;
        geoS[row][3]=sqrtf(jx*jx+jy*jy+jz*jz);
      }
      float sm  = wred32(pv4.x+pv4.y+pv4.z+pv4.w);
      float sm2 = wred32(pv4.x*pv4.x+pv4.y*pv4.y+pv4.z*pv4.z+pv4.w*pv4.w);
      float mu = sm*(1.f/128.f);
      float var = sm2*(1.f/128.f)-mu*mu;
      float rs = rsqrtf(var+EPSLN);
      rsA[jc]=rs; rmA[jc]=rs*mu;
    }
    // ---- edge GEMV over raw p with folded weights; LN fold at the end ----
    float ea0[4], ea1[4];
    #pragma unroll
    for (int jc=0;jc<4;jc++){ ea0[jc]=0.f; ea1[jc]=0.f; }
    for (int qb=0; qb<16; ++qb){
      const uint4 wv = *(const uint4*)&GwL[qb*128 + t*4];
      #pragma unroll
      for (int jc=0;jc<4;jc++){
        const uint4 pv = *(const uint4*)&pnH[wrow + r*4 + jc][8*qb];
        ea0[jc]=FDOT2(asH2(wv.y), asH2(pv.y), FDOT2(asH2(wv.x), asH2(pv.x), ea0[jc]));
        ea1[jc]=FDOT2(asH2(wv.w), asH2(pv.w), FDOT2(asH2(wv.z), asH2(pv.z), ea1[jc]));
      }
    }
    // e (pre-LN edge incl. bias) -> eH immediately; its LN reductions overlap a-GEMV
    float rs2A[4], rm2A[4];
    #pragma unroll
    for (int jc=0;jc<4;jc++){
      float e = rsA[jc]*(ea0[jc]+ea1[jc]) - rmA[jc]*gwS[t] + bwS[t];
      eH[wrow + r*4 + jc][t] = (_Float16)e;
      float sm=wred32(e), sm2=wred32(e*e);
      float mu=sm*(1.f/32.f), var=sm2*(1.f/32.f)-mu*mu;
      float rs2=rsqrtf(var+EPSLN);
      rs2A[jc]=rs2; rm2A[jc]=rs2*mu;
    }
    // ---- a = relu(rs2*(e·Gwa) − rs2*mu2*gwa + bwa + dist*waD) ----
    float av[4];
    #pragma unroll
    for (int jc=0;jc<4;jc++) av[jc]=0.f;
    for (int qb=0; qb<4; ++qb){
      const uint4 wv = *(const uint4*)&GwaL[qb*128 + t*4];
      #pragma unroll
      for (int jc=0;jc<4;jc++){
        const uint4 ev = *(const uint4*)&eH[wrow + r*4 + jc][8*qb];
        av[jc]=FDOT2(asH2(wv.w), asH2(ev.w), FDOT2(asH2(wv.z), asH2(ev.z),
                FDOT2(asH2(wv.y), asH2(ev.y), FDOT2(asH2(wv.x), asH2(ev.x), av[jc]))));
      }
    }
    #pragma unroll
    for (int jc=0;jc<4;jc++){
      float a = rs2A[jc]*av[jc] - rm2A[jc]*gwaS[t] + bwaS[t]
              + geoS[wrow + r*4 + jc][3]*waDS[t];
      aH[wrow + r*4 + jc][t]=(_Float16)fmaxf(a,0.f);
    }
    // ---- m0: a-part lanes t<16 (W0 blocks 0..3), node-part t>=16 (blocks 8..11) ----
    {
      const int half = t>>4, tc = t&15;
      const int wb = half ? 8 : 0;
      const float m0b = half ? 0.f : m0bG[item*16+tc];
      float m0v[4];
      #pragma unroll
      for (int jc=0;jc<4;jc++) m0v[jc]=m0b;
      for (int qb=0;qb<4;++qb){
        const uint4 wv = *(const uint4*)&W0L[(wb+qb)*64 + tc*4];
        #pragma unroll
        for (int jc=0;jc<4;jc++){
          const _Float16* opb = half ? &ndH[wrow + r*4 + jc][0] : &aH[wrow + r*4 + jc][0];
          const uint4 ov = *(const uint4*)&opb[8*qb];
          m0v[jc]=FDOT2(asH2(wv.w), asH2(ov.w), FDOT2(asH2(wv.z), asH2(ov.z),
                   FDOT2(asH2(wv.y), asH2(ov.y), FDOT2(asH2(wv.x), asH2(ov.x), m0v[jc]))));
        }
      }
      #pragma unroll
      for (int jc=0;jc<4;jc++){
        float tot = m0v[jc] + __shfl_xor(m0v[jc], 16);
        if (t<16 && vals[jc]) stA += fmaxf(tot, 0.f);
      }
    }
    // ---- c1/c2 from a ----
    {
      const bool up = (t>=12 && t<24);
      const int tc12 = up ? t-12 : (t<12 ? t : 0);
      const int wb = up ? 2 : 0;
      const int koff = up ? 16 : 0;
      float cv[4]={0.f,0.f,0.f,0.f};
      for (int qb=0;qb<2;++qb){
        const uint4 wv = *(const uint4*)&WcL[(wb+qb)*48 + tc12*4];
        #pragma unroll
        for (int jc=0;jc<4;jc++){
          const uint4 av2 = *(const uint4*)&aH[wrow + r*4 + jc][koff + 8*qb];
          cv[jc]=FDOT2(asH2(wv.w), asH2(av2.w), FDOT2(asH2(wv.z), asH2(av2.z),
                  FDOT2(asH2(wv.y), asH2(av2.y), FDOT2(asH2(wv.x), asH2(av2.x), cv[jc]))));
        }
      }
      #pragma unroll
      for (int jc=0;jc<4;jc++){
        const int src = (t<12) ? t+12 : (up ? t-12 : t);
        float other = __shfl(cv[jc], src, 32);
        if (t<12) cS[(wrow + r*4 + jc)*12+t] = cv[jc]+other;
      }
    }
    // ---- offset accumulation (t<9) ----
    if (t<9){
      const int o=t/3, x=t-o*3;
      #pragma unroll
      for (int jc=0;jc<4;jc++){
        if (!vals[jc]) continue;
        const int row = wrow + r*4 + jc;
        const float dj = geoS[row][3];
        const float dh = geoS[row][x]/(dj+1e-8f);
        const float* cr = &cS[row*12];
        float val = cr[o]*dh;
        const float caxj = xjS[row][3+x];
        #pragma unroll
        for (int c=0;c<3;c++){
          val += cr[3+o*3+c]*(xjS[row][c*3+x]-caxj);
        }
        ofA += val;
      }
    }
  }

  // ---- write this slice's partial (zeros if slice empty) ----
  stA += __shfl_xor(stA, 32);
  ofA += __shfl_xor(ofA, 32);
  if (wl < 16) part[s*28 + wl] = stA;
  if (wl < 9)  part[s*28 + 16 + wl] = ofA;
}

// ---------------- Kernel F: combine partials, scale by deg, form xyz_new ----------------
// grid = B*L (512), block = 64
__global__ __launch_bounds__(64) void k_fin(
    const float* __restrict__ xyz, const int* __restrict__ cnt,
    const float* __restrict__ part, float* __restrict__ out)
{
  const int bid = blockIdx.x;
  const int t = threadIdx.x;
  __shared__ float offF[9];
  const int n = cnt[bid];
  const float invd = 1.f/fmaxf((float)n,1.f);
  if (t<16){
    float s=0.f;
    #pragma unroll
    for (int k2=0;k2<SLI;k2++) s += part[(bid*SLI+k2)*28 + t];
    out[4608 + bid*16 + t] = s*invd;           // state
  } else if (t<25){
    float s=0.f;
    #pragma unroll
    for (int k2=0;k2<SLI;k2++) s += part[(bid*SLI+k2)*28 + t];
    offF[t-16] = s*invd;
  }
  __syncthreads();
  if (t<9){
    const int o=t/3, x=t-o*3;
    const float cac = xyz[(bid*3+1)*3+x];
    const float CA = cac + offF[3+x];          // offset[:,:,1]
    const float v = (o==1)? CA : (CA + offF[o*3+x]);
    out[bid*9 + t] = v;                        // xyz_new
  }
}

extern "C" void kernel_launch(void* const* d_in, const int* in_sizes, int n_in,
                              void* d_out, int out_size, void* d_ws, size_t ws_size,
                              hipStream_t stream)
{
  const float* msa     = (const float*)d_in[0];
  const float* pair    = (const float*)d_in[1];
  const float* xyz     = (const float*)d_in[2];
  const float* seq1hot = (const float*)d_in[3];
  const float* g_msa   = (const float*)d_in[4];
  const float* b_msa   = (const float*)d_in[5];
  const float* g_pair  = (const float*)d_in[6];
  const float* b_pair  = (const float*)d_in[7];
  const float* Wq      = (const float*)d_in[8];
  const float* bq      = (const float*)d_in[9];
  const float* Wk      = (const float*)d_in[10];
  const float* bk      = (const float*)d_in[11];
  const float* Wx      = (const float*)d_in[12];
  const float* bx      = (const float*)d_in[13];
  const float* g_node  = (const float*)d_in[14];
  const float* b_node  = (const float*)d_in[15];
  const float* We      = (const float*)d_in[16];
  const float* be      = (const float*)d_in[17];
  const float* g_edge  = (const float*)d_in[18];
  const float* b_edge  = (const float*)d_in[19];
  const float* Wa      = (const float*)d_in[20];
  const float* ba      = (const float*)d_in[21];
  const float* W0      = (const float*)d_in[22];
  const float* b0      = (const float*)d_in[23];
  const float* Wc1     = (const float*)d_in[24];
  const float* Wc2     = (const float*)d_in[25];
  const int*   idx     = (const int*)d_in[26];
  const int*   topk    = (const int*)d_in[27];
  float* out = (float*)d_out;

  float* wsf = (float*)d_ws;
  float*    node  = wsf + WS_NODE;
  int*      cnt   = (int*)(wsf + WS_CNT);
  int*      jlist = (int*)(wsf + WS_JLIST);
  float*    m0bG  = wsf + WS_M0B;
  float*    partb = wsf + WS_PART;
  unsigned* packW = (unsigned*)(wsf + WS_PACKW);

  k_prep<<<512, 512, 0, stream>>>(msa, seq1hot, xyz, idx, topk, g_msa, b_msa,
                                  g_pair, b_pair, Wq, bq, Wk, bk, Wx, bx,
                                  g_node, b_node, We, be, g_edge, b_edge,
                                  Wa, ba, W0, b0, Wc1, Wc2,
                                  node, cnt, jlist, m0bG, packW);
  k_main<<<512*SLI/4, 256, 0, stream>>>(pair, xyz, node, cnt, jlist, m0bG,
                                        packW, partb);
  k_fin<<<512, 64, 0, stream>>>(xyz, cnt, partb, out);
}

// Round 11
// 50.393 us; speedup vs baseline: 3.1045x; 1.0081x over previous
//
#include <hip/hip_runtime.h>

#define EPSLN 1e-5f
#define KMINC 9
#define SLI   10         // slices per (b,i), 8 rows each -> covers n <= 80

typedef _Float16 h2 __attribute__((ext_vector_type(2)));
typedef _Float16 h4 __attribute__((ext_vector_type(4)));

#if defined(__has_builtin)
#if __has_builtin(__builtin_amdgcn_fdot2)
#define FDOT2(a,b,c) __builtin_amdgcn_fdot2((a),(b),(c),false)
#endif
#endif
#ifndef FDOT2
#define FDOT2(a,b,c) ((c) + (float)(a)[0]*(float)(b)[0] + (float)(a)[1]*(float)(b)[1])
#endif

__device__ __forceinline__ h2 mk2(float a, float b){
  h2 v; v[0]=(_Float16)a; v[1]=(_Float16)b; return v;
}
__device__ __forceinline__ unsigned h2bits(h2 v){
  union { h2 h; unsigned u; } c; c.h = v; return c.u;
}
__device__ __forceinline__ h2 asH2(unsigned u){
  union { unsigned u; h2 h; } c; c.u = u; return c.h;
}

__device__ __forceinline__ float wred64(float v){
  #pragma unroll
  for (int m=1;m<64;m<<=1) v += __shfl_xor(v,m,64);
  return v;
}
__device__ __forceinline__ float wred32(float v){
  #pragma unroll
  for (int m=1;m<32;m<<=1) v += __shfl_xor(v,m,64);
  return v;
}

// ws word-offsets
#define WS_NODE   0            // 16384 f32
#define WS_CNT    16384        // 512 i32
#define WS_JLIST  16896        // 512*96 i32 -> ends 66048
#define WS_M0B    66048        // 512*16 f32 -> ends 74240
#define WS_PACKW  74240        // 3520 u32 weights + 160 f32 consts

// packW layout (u32 words):
//  [0,2048)    GwP  = diag(g_pair)@We, q-blocked f16 pairs
//  [2048,2560) GwaP = diag(g_edge)@Wa, q-blocked
//  [2560,3328) W0P q-blocked
//  [3328,3520) WcP q-blocked
//  f32: [3520) waD[32], [3552) gw[32], [3584) bw[32], [3616) gwa[32], [3648) bwa[32]

// ---------------- Kernel P: msa-LN/attention/node + m0b + top-k mask + weight fold/pack ----------------
// grid = B*L (512), block = 512 (8 waves)
__global__ __launch_bounds__(512) void k_prep(
    const float* __restrict__ msa, const float* __restrict__ seq1hot,
    const float* __restrict__ xyz, const int* __restrict__ idxp,
    const int* __restrict__ topk,
    const float* __restrict__ g_msa, const float* __restrict__ b_msa,
    const float* __restrict__ g_pair, const float* __restrict__ b_pair,
    const float* __restrict__ Wq, const float* __restrict__ bq,
    const float* __restrict__ Wk, const float* __restrict__ bk,
    const float* __restrict__ Wx, const float* __restrict__ bx,
    const float* __restrict__ g_node, const float* __restrict__ b_node,
    const float* __restrict__ We, const float* __restrict__ be,
    const float* __restrict__ g_edge, const float* __restrict__ b_edge,
    const float* __restrict__ Wa, const float* __restrict__ ba,
    const float* __restrict__ W0, const float* __restrict__ b0,
    const float* __restrict__ Wc1, const float* __restrict__ Wc2,
    float* __restrict__ node, int* __restrict__ cnt, int* __restrict__ jlist,
    float* __restrict__ m0bG, unsigned* __restrict__ packW)
{
  const int bid = blockIdx.x;          // b*256 + l  (l == i)
  const int b = bid >> 8;
  const int tid = threadIdx.x;
  const int w = tid >> 6, lane = tid & 63;   // 8 waves

  __shared__ float mn[32][64];
  __shared__ float qS[64];
  __shared__ float scS[32];
  __shared__ float redS[8][64];
  __shared__ float ssumS[8];
  __shared__ float nodeS[32];
  __shared__ alignas(16) float Dv[256];
  __shared__ int   wsum[4];

  // ---- block 0: LN-folded weight packing ----
  if (bid==0){
    for (int i=tid;i<2048;i+=512){
      int qb=i>>7, r7=i&127, t=r7>>2, i2=r7&3, q=4*qb+i2;
      packW[i] = h2bits(mk2(g_pair[2*q]*We[(2*q)*32+t], g_pair[2*q+1]*We[(2*q+1)*32+t]));
    }
    for (int i=tid;i<512; i+=512){
      int qb=i>>7, r7=i&127, t=r7>>2, i2=r7&3, q=4*qb+i2;
      packW[2048+i] = h2bits(mk2(g_edge[2*q]*Wa[(2*q)*32+t], g_edge[2*q+1]*Wa[(2*q+1)*32+t]));
    }
    for (int i=tid;i<768; i+=512){
      int qb=i>>6, r6=i&63, tc=r6>>2, i2=r6&3, q=4*qb+i2;
      packW[2560+i] = h2bits(mk2(W0[(2*q)*16+tc], W0[(2*q+1)*16+tc]));
    }
    if (tid<192){
      int qb=tid/48, r48=tid%48, tc=r48>>2, i2=r48&3, q=4*qb+i2;
      float lo = (tc<3)? Wc1[(2*q)*3+tc]   : Wc2[(2*q)*9+(tc-3)];
      float hi = (tc<3)? Wc1[(2*q+1)*3+tc] : Wc2[(2*q+1)*9+(tc-3)];
      packW[3328+tid] = h2bits(mk2(lo,hi));
    }
    if (tid<32){
      float* pf = (float*)packW;
      pf[3520+tid] = Wa[32*32+tid];                       // waD
      float gw=0.f, bw=0.f;
      for (int k=0;k<128;k++){
        gw += g_pair[k]*We[k*32+tid];
        bw += b_pair[k]*We[k*32+tid];
      }
      pf[3552+tid] = gw;
      pf[3584+tid] = bw + be[tid];
      float gwa=0.f, bwa=0.f;
      for (int c=0;c<32;c++){
        gwa += g_edge[c]*Wa[c*32+tid];
        bwa += b_edge[c]*Wa[c*32+tid];
      }
      pf[3616+tid] = gwa;
      pf[3648+tid] = bwa + ba[tid];
    }
  }

  // ---- msa LN: wave w rows w, w+8, w+16, w+24 ----
  const float gm = g_msa[lane], bm = b_msa[lane];
  for (int nn=w; nn<32; nn+=8){
    float x = msa[(size_t)(((b*32+nn)<<8)+(bid&255))*64 + lane];
    float s = wred64(x), s2 = wred64(x*x);
    float mu = s*(1.f/64.f);
    float var = s2*(1.f/64.f) - mu*mu;
    mn[nn][lane] = (x-mu)*rsqrtf(var+EPSLN)*gm + bm;
  }
  __syncthreads();
  {
    float p = (w==0)? bq[lane] : 0.f;
    for (int d=w*8; d<w*8+8; d++) p += mn[0][d]*Wq[d*64+lane];
    redS[w][lane] = p;
  }
  __syncthreads();
  if (w==0){
    float q = 0.f;
    #pragma unroll
    for (int k=0;k<8;k++) q += redS[k][lane];
    qS[lane] = q*0.125f;               // 1/sqrt(64)
  }
  __syncthreads();
  {
    float p = 0.f;
    for (int e=w*8; e<w*8+8; e++) p += Wk[lane*64+e]*qS[e];
    redS[w][lane] = p;
  }
  __syncthreads();
  float qk = 0.f;
  #pragma unroll
  for (int k=0;k<8;k++) qk += redS[k][lane];
  const float qb_ = wred64(qS[lane]*bk[lane]);
  for (int nn=w*4; nn<w*4+4; nn++){
    float p = wred64(mn[nn][lane]*qk);
    if (lane==0) scS[nn] = p + qb_;
  }
  __syncthreads();
  float mx = -1e30f;
  for (int nn=0; nn<32; nn++) mx = fmaxf(mx, scS[nn]);
  float ps=0.f, pm=0.f;
  for (int nn=w*4; nn<w*4+4; nn++){
    float e = expf(scS[nn]-mx);
    ps += e; pm += e*mn[nn][lane];
  }
  redS[w][lane] = pm;
  if (lane==0) ssumS[w] = ps;
  __syncthreads();
  if (w==0){
    float ssum = 0.f, acc = 0.f;
    #pragma unroll
    for (int k=0;k<8;k++){ ssum += ssumS[k]; acc += redS[k][lane]; }
    qS[lane] = acc / ssum;
  }
  __syncthreads();
  if (tid<32){
    float acc = bx[tid];
    for (int k=0;k<64;k++) acc += qS[k]*Wx[k*32+tid];
    const float* s1 = &seq1hot[bid*21];
    for (int k=0;k<21;k++) acc += s1[k]*Wx[(64+k)*32+tid];
    float s = wred32(acc), s2 = wred32(acc*acc);
    float mu = s*(1.f/32.f), var = s2*(1.f/32.f)-mu*mu;
    float v = (acc-mu)*rsqrtf(var+EPSLN)*g_node[tid] + b_node[tid];
    node[bid*32+tid] = v;
    nodeS[tid] = v;
  }
  __syncthreads();
  if (tid<16){
    float acc = b0[tid];
    for (int k=0;k<32;k++) acc += nodeS[k]*W0[(32+k)*16+tid];
    m0bG[bid*16+tid] = acc;
  }

  // --- Phase 2: distances, exact stable top-k rank, compaction (tid<256, thread=j) ---
  const bool act = tid < 256;
  const int i = bid & 255;
  const int j = tid;
  float D = 0.f;
  if (act){
    const float cax = xyz[(bid*3+1)*3+0];
    const float cay = xyz[(bid*3+1)*3+1];
    const float caz = xyz[(bid*3+1)*3+2];
    const int jb = (b<<8)+j;
    float dx = xyz[(jb*3+1)*3+0]-cax;
    float dy = xyz[(jb*3+1)*3+1]-cay;
    float dz = xyz[(jb*3+1)*3+2]-caz;
    D = sqrtf(dx*dx+dy*dy+dz*dz) + (i==j ? 999.9f : 0.f);
  }
  __syncthreads();
  if (act) Dv[j] = D;
  __syncthreads();
  if (act){
    int rank = 0;
    for (int j2=0;j2<256;j2+=4){
      const float4 dv = *(const float4*)&Dv[j2];
      rank += (dv.x < D || (dv.x == D && (j2+0) < j)) ? 1 : 0;
      rank += (dv.y < D || (dv.y == D && (j2+1) < j)) ? 1 : 0;
      rank += (dv.z < D || (dv.z == D && (j2+2) < j)) ? 1 : 0;
      rank += (dv.w < D || (dv.w == D && (j2+3) < j)) ? 1 : 0;
    }
    int K = topk[0];
    if (K<=0 || K>256){
      float f = ((const float*)topk)[0];
      K = (f>=1.f && f<=256.f) ? (int)f : 64;
    }
    const int jb = (b<<8)+j;
    const int sep = abs(idxp[jb] - idxp[bid]);
    const bool m = (rank < K) || (i!=j && sep < KMINC);
    unsigned long long bal = __ballot(m);
    const int l6 = j & 63, wv = j >> 6;
    const int pre = __popcll(bal & ((1ull<<l6)-1ull));
    if (l6==0) wsum[wv] = __popcll(bal);
    __syncthreads();
    int off = 0;
    for (int w2=0;w2<wv;w2++) off += wsum[w2];
    if (m) jlist[bid*96 + off + pre] = j;
    if (j==0) cnt[bid] = wsum[0]+wsum[1]+wsum[2]+wsum[3];
  } else {
    __syncthreads();
  }
}

// ---------------- Kernel C: one block per item, 10 waves = 10 slices, in-block finish ----------------
// grid = B*L (512), block = 640 (10 waves). Wave w handles rows [8w, 8w+8) of the item's
// masked j-list; LDS ~58 KB -> exactly 2 blocks/CU, 20 waves/CU, SINGLE generation, no tail.
// Cross-slice combine is a plain __syncthreads + wave-0 LDS reduce (no fences/atomics,
// no k_fin kernel, no part round-trip). Deterministic (fixed slice order).
__global__ __launch_bounds__(640) void k_main(
    const float* __restrict__ pair, const float* __restrict__ xyz,
    const float* __restrict__ node, const int* __restrict__ cnt,
    const int* __restrict__ jlist, const float* __restrict__ m0bG,
    const unsigned* __restrict__ packW, float* __restrict__ out)
{
  const int tid = threadIdx.x;
  const int w  = tid >> 6;          // wave 0..9 == slice
  const int wl = tid & 63;          // lane in wave
  const int r  = (tid >> 5) & 1;    // group in wave
  const int t  = tid & 31;          // lane in group

  __shared__ alignas(16) unsigned GwL[2048];        // 8 KB
  __shared__ alignas(16) unsigned GwaL[512];        // 2 KB
  __shared__ alignas(16) unsigned W0L[768];         // 3 KB
  __shared__ alignas(16) unsigned WcL[192];         // 768 B
  __shared__ float waDS[32], gwS[32], bwS[32], gwaS[32], bwaS[32];
  __shared__ alignas(16) _Float16 pnH[80][128];     // 20 KB raw pair rows f16
  __shared__ alignas(16) _Float16 eH [80][32];      // 5 KB
  __shared__ alignas(16) _Float16 aH [80][32];      // 5 KB
  __shared__ alignas(16) _Float16 ndH[80][32];      // 5 KB
  __shared__ float cS[80*12];                       // 3.75 KB
  __shared__ float xjS[80][9];                      // 2.8 KB
  __shared__ float geoS[80][4];                     // 1.25 KB
  __shared__ float pstS[SLI][16];
  __shared__ float pofS[SLI][9];

  for (int i2=tid;i2<2048;i2+=640) GwL[i2] = packW[i2];
  for (int i2=tid;i2<512; i2+=640) GwaL[i2] = packW[2048+i2];
  for (int i2=tid;i2<768; i2+=640) W0L[i2] = packW[2560+i2];
  if (tid<192) WcL[tid] = packW[3328+tid];
  if (tid>=192 && tid<224){
    const int k = tid-192;
    const float* pf = (const float*)packW;
    waDS[k]=pf[3520+k]; gwS[k]=pf[3552+k]; bwS[k]=pf[3584+k];
    gwaS[k]=pf[3616+k]; bwaS[k]=pf[3648+k];
  }
  __syncthreads();

  const int item = blockIdx.x;         // (b,i)
  const int b    = item >> 8;
  const int n    = cnt[item];
  const int row0 = w*8;                // this wave's rows (LDS row == slot)

  float stA = 0.f;
  float ofA = 0.f;

  if (row0 < n){
    const float cax = xyz[(item*3+1)*3+0];
    const float cay = xyz[(item*3+1)*3+1];
    const float caz = xyz[(item*3+1)*3+2];
    bool vals[4];
    int jjs[4];
    float4 pvv[4];
    // ---- issue ALL independent global loads first (latency head) ----
    #pragma unroll
    for (int jc=0;jc<4;jc++){
      const int slot = row0 + r*4 + jc;
      vals[jc] = slot < n;
      jjs[jc] = vals[jc] ? jlist[item*96 + slot] : 0;
    }
    #pragma unroll
    for (int jc=0;jc<4;jc++){
      const int row = row0 + r*4 + jc;
      pvv[jc] = *(const float4*)&pair[(((long)item*256 + jjs[jc])*128) + 4*t];
      const int jb=(b<<8)+jjs[jc];
      ndH[row][t] = (_Float16)node[jb*32+t];
      if (t<9) xjS[row][t] = xyz[(size_t)jb*9 + t];
      if (t==0){
        float jx = xyz[(size_t)jb*9+3]-cax;
        float jy = xyz[(size_t)jb*9+4]-cay;
        float jz = xyz[(size_t)jb*9+5]-caz;
        geoS[row][0]=jx; geoS[row][1]=jy; geoS[row][2]=jz;
        geoS[row][3]=sqrtf(jx*jx+jy*jy+jz*jz);
      }
    }
    // ---- convert+stage + LN stats ----
    float rsA[4], rmA[4];
    #pragma unroll
    for (int jc=0;jc<4;jc++){
      const int row = row0 + r*4 + jc;
      const float4 pv4 = pvv[jc];
      h4 o;
      o[0]=(_Float16)pv4.x; o[1]=(_Float16)pv4.y;
      o[2]=(_Float16)pv4.z; o[3]=(_Float16)pv4.w;
      *(h4*)&pnH[row][4*t] = o;
      float sm  = wred32(pv4.x+pv4.y+pv4.z+pv4.w);
      float sm2 = wred32(pv4.x*pv4.x+pv4.y*pv4.y+pv4.z*pv4.z+pv4.w*pv4.w);
      float mu = sm*(1.f/128.f);
      float var = sm2*(1.f/128.f)-mu*mu;
      float rs = rsqrtf(var+EPSLN);
      rsA[jc]=rs; rmA[jc]=rs*mu;
    }
    // ---- edge GEMV over raw p with folded weights; LN fold at the end ----
    float ea0[4], ea1[4];
    #pragma unroll
    for (int jc=0;jc<4;jc++){ ea0[jc]=0.f; ea1[jc]=0.f; }
    for (int qb=0; qb<16; ++qb){
      const uint4 wv = *(const uint4*)&GwL[qb*128 + t*4];
      #pragma unroll
      for (int jc=0;jc<4;jc++){
        const uint4 pv = *(const uint4*)&pnH[row0 + r*4 + jc][8*qb];
        ea0[jc]=FDOT2(asH2(wv.y), asH2(pv.y), FDOT2(asH2(wv.x), asH2(pv.x), ea0[jc]));
        ea1[jc]=FDOT2(asH2(wv.w), asH2(pv.w), FDOT2(asH2(wv.z), asH2(pv.z), ea1[jc]));
      }
    }
    // e (pre-LN edge incl. bias) -> eH; its LN stats overlap the next GEMV
    float rs2A[4], rm2A[4];
    #pragma unroll
    for (int jc=0;jc<4;jc++){
      float e = rsA[jc]*(ea0[jc]+ea1[jc]) - rmA[jc]*gwS[t] + bwS[t];
      eH[row0 + r*4 + jc][t] = (_Float16)e;
      float sm=wred32(e), sm2=wred32(e*e);
      float mu=sm*(1.f/32.f), var=sm2*(1.f/32.f)-mu*mu;
      float rs2=rsqrtf(var+EPSLN);
      rs2A[jc]=rs2; rm2A[jc]=rs2*mu;
    }
    // ---- a = relu(rs2*(e·Gwa) − rs2*mu2*gwa + bwa + dist*waD) ----
    float av[4];
    #pragma unroll
    for (int jc=0;jc<4;jc++) av[jc]=0.f;
    for (int qb=0; qb<4; ++qb){
      const uint4 wv = *(const uint4*)&GwaL[qb*128 + t*4];
      #pragma unroll
      for (int jc=0;jc<4;jc++){
        const uint4 ev = *(const uint4*)&eH[row0 + r*4 + jc][8*qb];
        av[jc]=FDOT2(asH2(wv.w), asH2(ev.w), FDOT2(asH2(wv.z), asH2(ev.z),
                FDOT2(asH2(wv.y), asH2(ev.y), FDOT2(asH2(wv.x), asH2(ev.x), av[jc]))));
      }
    }
    #pragma unroll
    for (int jc=0;jc<4;jc++){
      float a = rs2A[jc]*av[jc] - rm2A[jc]*gwaS[t] + bwaS[t]
              + geoS[row0 + r*4 + jc][3]*waDS[t];
      aH[row0 + r*4 + jc][t]=(_Float16)fmaxf(a,0.f);
    }
    // ---- m0: a-part lanes t<16 (W0 blocks 0..3), node-part t>=16 (blocks 8..11) ----
    {
      const int half = t>>4, tc = t&15;
      const int wb = half ? 8 : 0;
      const float m0b = half ? 0.f : m0bG[item*16+tc];
      float m0v[4];
      #pragma unroll
      for (int jc=0;jc<4;jc++) m0v[jc]=m0b;
      for (int qb=0;qb<4;++qb){
        const uint4 wv = *(const uint4*)&W0L[(wb+qb)*64 + tc*4];
        #pragma unroll
        for (int jc=0;jc<4;jc++){
          const _Float16* opb = half ? &ndH[row0 + r*4 + jc][0] : &aH[row0 + r*4 + jc][0];
          const uint4 ov = *(const uint4*)&opb[8*qb];
          m0v[jc]=FDOT2(asH2(wv.w), asH2(ov.w), FDOT2(asH2(wv.z), asH2(ov.z),
                   FDOT2(asH2(wv.y), asH2(ov.y), FDOT2(asH2(wv.x), asH2(ov.x), m0v[jc]))));
        }
      }
      #pragma unroll
      for (int jc=0;jc<4;jc++){
        float tot = m0v[jc] + __shfl_xor(m0v[jc], 16);
        if (t<16 && vals[jc]) stA += fmaxf(tot, 0.f);
      }
    }
    // ---- c1/c2 from a ----
    {
      const bool up = (t>=12 && t<24);
      const int tc12 = up ? t-12 : (t<12 ? t : 0);
      const int wb = up ? 2 : 0;
      const int koff = up ? 16 : 0;
      float cv[4]={0.f,0.f,0.f,0.f};
      for (int qb=0;qb<2;++qb){
        const uint4 wv = *(const uint4*)&WcL[(wb+qb)*48 + tc12*4];
        #pragma unroll
        for (int jc=0;jc<4;jc++){
          const uint4 av2 = *(const uint4*)&aH[row0 + r*4 + jc][koff + 8*qb];
          cv[jc]=FDOT2(asH2(wv.w), asH2(av2.w), FDOT2(asH2(wv.z), asH2(av2.z),
                  FDOT2(asH2(wv.y), asH2(av2.y), FDOT2(asH2(wv.x), asH2(av2.x), cv[jc]))));
        }
      }
      #pragma unroll
      for (int jc=0;jc<4;jc++){
        const int src = (t<12) ? t+12 : (up ? t-12 : t);
        float other = __shfl(cv[jc], src, 32);
        if (t<12) cS[(row0 + r*4 + jc)*12+t] = cv[jc]+other;
      }
    }
    // ---- offset accumulation (t<9) ----
    if (t<9){
      const int o=t/3, x=t-o*3;
      #pragma unroll
      for (int jc=0;jc<4;jc++){
        if (!vals[jc]) continue;
        const int row = row0 + r*4 + jc;
        const float dj = geoS[row][3];
        const float dh = geoS[row][x]/(dj+1e-8f);
        const float* cr = &cS[row*12];
        float val = cr[o]*dh;
        const float caxj = xjS[row][3+x];
        #pragma unroll
        for (int c=0;c<3;c++){
          val += cr[3+o*3+c]*(xjS[row][c*3+x]-caxj);
        }
        ofA += val;
      }
    }
  }

  // ---- combine wave's two groups, stash slice partial in LDS ----
  stA += __shfl_xor(stA, 32);
  ofA += __shfl_xor(ofA, 32);
  if (wl < 16) pstS[w][wl] = stA;
  if (wl < 9)  pofS[w][wl] = ofA;
  __syncthreads();

  // ---- in-block finisher (wave 0, fixed slice order -> deterministic) ----
  if (tid < 64){
    const float invd = 1.f/fmaxf((float)n,1.f);
    float sst=0.f, sof=0.f;
    #pragma unroll
    for (int k2=0;k2<SLI;k2++){
      if (wl<16) sst += pstS[k2][wl];
      if (wl<9)  sof += pofS[k2][wl];
    }
    if (wl<16) out[4608 + item*16 + wl] = sst*invd;      // state
    const float off = sof*invd;                           // off[wl] (wl<9)
    const int x = wl - (wl/3)*3;                          // wl%3
    const float offca = __shfl(off, 3+x, 64);             // off[3+x]
    if (wl<9){
      const float cac = xyz[(item*3+1)*3 + x];
      const float CA = cac + offca;
      const int o = wl/3;
      out[item*9 + wl] = (o==1)? CA : (CA + off);         // xyz_new
    }
  }
}

extern "C" void kernel_launch(void* const* d_in, const int* in_sizes, int n_in,
                              void* d_out, int out_size, void* d_ws, size_t ws_size,
                              hipStream_t stream)
{
  const float* msa     = (const float*)d_in[0];
  const float* pair    = (const float*)d_in[1];
  const float* xyz     = (const float*)d_in[2];
  const float* seq1hot = (const float*)d_in[3];
  const float* g_msa   = (const float*)d_in[4];
  const float* b_msa   = (const float*)d_in[5];
  const float* g_pair  = (const float*)d_in[6];
  const float* b_pair  = (const float*)d_in[7];
  const float* Wq      = (const float*)d_in[8];
  const float* bq      = (const float*)d_in[9];
  const float* Wk      = (const float*)d_in[10];
  const float* bk      = (const float*)d_in[11];
  const float* Wx      = (const float*)d_in[12];
  const float* bx      = (const float*)d_in[13];
  const float* g_node  = (const float*)d_in[14];
  const float* b_node  = (const float*)d_in[15];
  const float* We      = (const float*)d_in[16];
  const float* be      = (const float*)d_in[17];
  const float* g_edge  = (const float*)d_in[18];
  const float* b_edge  = (const float*)d_in[19];
  const float* Wa      = (const float*)d_in[20];
  const float* ba      = (const float*)d_in[21];
  const float* W0      = (const float*)d_in[22];
  const float* b0      = (const float*)d_in[23];
  const float* Wc1     = (const float*)d_in[24];
  const float* Wc2     = (const float*)d_in[25];
  const int*   idx     = (const int*)d_in[26];
  const int*   topk    = (const int*)d_in[27];
  float* out = (float*)d_out;

  float* wsf = (float*)d_ws;
  float*    node  = wsf + WS_NODE;
  int*      cnt   = (int*)(wsf + WS_CNT);
  int*      jlist = (int*)(wsf + WS_JLIST);
  float*    m0bG  = wsf + WS_M0B;
  unsigned* packW = (unsigned*)(wsf + WS_PACKW);

  k_prep<<<512, 512, 0, stream>>>(msa, seq1hot, xyz, idx, topk, g_msa, b_msa,
                                  g_pair, b_pair, Wq, bq, Wk, bk, Wx, bx,
                                  g_node, b_node, We, be, g_edge, b_edge,
                                  Wa, ba, W0, b0, Wc1, Wc2,
                                  node, cnt, jlist, m0bG, packW);
  k_main<<<512, 640, 0, stream>>>(pair, xyz, node, cnt, jlist, m0bG,
                                  packW, out);
}

// Round 12
// 48.955 us; speedup vs baseline: 3.1957x; 1.0294x over previous
//
#include <hip/hip_runtime.h>

#define EPSLN 1e-5f
#define KMINC 9
#define NW    5          // waves per item-block; wave = one 16-row M-tile (80 slots)

typedef _Float16 h2 __attribute__((ext_vector_type(2)));
typedef _Float16 h4 __attribute__((ext_vector_type(4)));
typedef _Float16 h8 __attribute__((ext_vector_type(8)));
typedef float f32x4 __attribute__((ext_vector_type(4)));

__device__ __forceinline__ h2 mk2(float a, float b){
  h2 v; v[0]=(_Float16)a; v[1]=(_Float16)b; return v;
}
__device__ __forceinline__ unsigned h2bits(h2 v){
  union { h2 h; unsigned u; } c; c.h = v; return c.u;
}
__device__ __forceinline__ h8 asH8(uint4 u){
  union { uint4 u; h8 h; } c; c.u = u; return c.h;
}

__device__ __forceinline__ float wred64(float v){
  #pragma unroll
  for (int m=1;m<64;m<<=1) v += __shfl_xor(v,m,64);
  return v;
}
__device__ __forceinline__ float wred32(float v){
  #pragma unroll
  for (int m=1;m<32;m<<=1) v += __shfl_xor(v,m,64);
  return v;
}

// ws word-offsets
#define WS_NODE   0            // 16384 f32
#define WS_CNT    16384        // 512 i32
#define WS_JLIST  16896        // 512*96 i32 -> ends 66048
#define WS_M0B    66048        // 512*16 f32 -> ends 74240
#define WS_PACKW  74240        // 3328 u32 (B-frag weights, swizzle baked) + 160 f32 consts

// packW v2 (u32 words), all f16 B-operand layout [col][k] with XOR swizzle baked in:
//  [0,2048)    GwB  = diag(g_pair)@We  [32 col][128 k], byte=col*256+((2k)^((col&7)<<4))
//  [2048,2560) GwaB = diag(g_edge)@Wa  [32 col][32 k],  byte=col*64 +((2k)^((col&3)<<4))
//  [2560,2816) W0aB = W0 rows 0..31    [16 col][32 k],  same 64B-row swizzle
//  [2816,3072) W0cB = W0 rows 64..95   [16 col][32 k]
//  [3072,3328) WcB  = [Wc1|Wc2|0pad]   [16 col][32 k]
//  f32: [3328) waD[32], [3360) gw[32], [3392) bw[32], [3424) gwa[32], [3456) bwa[32]

// ---------------- Kernel P: msa-LN/attention/node + m0b + top-k mask + weight fold/pack ----------------
// grid = B*L (512), block = 512 (8 waves)
__global__ __launch_bounds__(512) void k_prep(
    const float* __restrict__ msa, const float* __restrict__ seq1hot,
    const float* __restrict__ xyz, const int* __restrict__ idxp,
    const int* __restrict__ topk,
    const float* __restrict__ g_msa, const float* __restrict__ b_msa,
    const float* __restrict__ g_pair, const float* __restrict__ b_pair,
    const float* __restrict__ Wq, const float* __restrict__ bq,
    const float* __restrict__ Wk, const float* __restrict__ bk,
    const float* __restrict__ Wx, const float* __restrict__ bx,
    const float* __restrict__ g_node, const float* __restrict__ b_node,
    const float* __restrict__ We, const float* __restrict__ be,
    const float* __restrict__ g_edge, const float* __restrict__ b_edge,
    const float* __restrict__ Wa, const float* __restrict__ ba,
    const float* __restrict__ W0, const float* __restrict__ b0,
    const float* __restrict__ Wc1, const float* __restrict__ Wc2,
    float* __restrict__ node, int* __restrict__ cnt, int* __restrict__ jlist,
    float* __restrict__ m0bG, unsigned* __restrict__ packW)
{
  const int bid = blockIdx.x;          // b*256 + l  (l == i)
  const int b = bid >> 8;
  const int tid = threadIdx.x;
  const int w = tid >> 6, lane = tid & 63;   // 8 waves

  __shared__ float mn[32][64];
  __shared__ float qS[64];
  __shared__ float scS[32];
  __shared__ float redS[8][64];
  __shared__ float ssumS[8];
  __shared__ float nodeS[32];
  __shared__ alignas(16) float Dv[256];
  __shared__ int   wsum[4];

  // ---- block 0: LN-folded weight packing, B-frag layout, swizzle baked ----
  if (bid==0){
    for (int i=tid;i<2048;i+=512){
      int col=i>>6, wd=i&63, m=wd^((col&7)<<2), k0=2*m;
      packW[i] = h2bits(mk2(g_pair[k0]*We[k0*32+col], g_pair[k0+1]*We[(k0+1)*32+col]));
    }
    if (tid<512){
      int i=tid, col=i>>4, wd=i&15, m=wd^((col&3)<<2), k0=2*m;
      packW[2048+i] = h2bits(mk2(g_edge[k0]*Wa[k0*32+col], g_edge[k0+1]*Wa[(k0+1)*32+col]));
    }
    if (tid<256){
      int i=tid, col=i>>4, wd=i&15, m=wd^((col&3)<<2), k0=2*m;
      packW[2560+i] = h2bits(mk2(W0[k0*16+col], W0[(k0+1)*16+col]));
      packW[2816+i] = h2bits(mk2(W0[(64+k0)*16+col], W0[(65+k0)*16+col]));
      float lo = (col<3)? Wc1[k0*3+col] : (col<12? Wc2[k0*9+(col-3)] : 0.f);
      float hi = (col<3)? Wc1[(k0+1)*3+col] : (col<12? Wc2[(k0+1)*9+(col-3)] : 0.f);
      packW[3072+i] = h2bits(mk2(lo,hi));
    }
    if (tid<32){
      float* pf = (float*)packW;
      pf[3328+tid] = Wa[32*32+tid];                       // waD
      float gw=0.f, bw=0.f;
      for (int k=0;k<128;k++){
        gw += g_pair[k]*We[k*32+tid];
        bw += b_pair[k]*We[k*32+tid];
      }
      pf[3360+tid] = gw;
      pf[3392+tid] = bw + be[tid];
      float gwa=0.f, bwa=0.f;
      for (int c=0;c<32;c++){
        gwa += g_edge[c]*Wa[c*32+tid];
        bwa += b_edge[c]*Wa[c*32+tid];
      }
      pf[3424+tid] = gwa;
      pf[3456+tid] = bwa + ba[tid];
    }
  }

  // ---- msa LN: wave w rows w, w+8, w+16, w+24 ----
  const float gm = g_msa[lane], bm = b_msa[lane];
  for (int nn=w; nn<32; nn+=8){
    float x = msa[(size_t)(((b*32+nn)<<8)+(bid&255))*64 + lane];
    float s = wred64(x), s2 = wred64(x*x);
    float mu = s*(1.f/64.f);
    float var = s2*(1.f/64.f) - mu*mu;
    mn[nn][lane] = (x-mu)*rsqrtf(var+EPSLN)*gm + bm;
  }
  __syncthreads();
  {
    float p = (w==0)? bq[lane] : 0.f;
    for (int d=w*8; d<w*8+8; d++) p += mn[0][d]*Wq[d*64+lane];
    redS[w][lane] = p;
  }
  __syncthreads();
  if (w==0){
    float q = 0.f;
    #pragma unroll
    for (int k=0;k<8;k++) q += redS[k][lane];
    qS[lane] = q*0.125f;               // 1/sqrt(64)
  }
  __syncthreads();
  {
    float p = 0.f;
    for (int e=w*8; e<w*8+8; e++) p += Wk[lane*64+e]*qS[e];
    redS[w][lane] = p;
  }
  __syncthreads();
  float qk = 0.f;
  #pragma unroll
  for (int k=0;k<8;k++) qk += redS[k][lane];
  const float qb_ = wred64(qS[lane]*bk[lane]);
  for (int nn=w*4; nn<w*4+4; nn++){
    float p = wred64(mn[nn][lane]*qk);
    if (lane==0) scS[nn] = p + qb_;
  }
  __syncthreads();
  float mx = -1e30f;
  for (int nn=0; nn<32; nn++) mx = fmaxf(mx, scS[nn]);
  float ps=0.f, pm=0.f;
  for (int nn=w*4; nn<w*4+4; nn++){
    float e = expf(scS[nn]-mx);
    ps += e; pm += e*mn[nn][lane];
  }
  redS[w][lane] = pm;
  if (lane==0) ssumS[w] = ps;
  __syncthreads();
  if (w==0){
    float ssum = 0.f, acc = 0.f;
    #pragma unroll
    for (int k=0;k<8;k++){ ssum += ssumS[k]; acc += redS[k][lane]; }
    qS[lane] = acc / ssum;
  }
  __syncthreads();
  if (tid<32){
    float acc = bx[tid];
    for (int k=0;k<64;k++) acc += qS[k]*Wx[k*32+tid];
    const float* s1 = &seq1hot[bid*21];
    for (int k=0;k<21;k++) acc += s1[k]*Wx[(64+k)*32+tid];
    float s = wred32(acc), s2 = wred32(acc*acc);
    float mu = s*(1.f/32.f), var = s2*(1.f/32.f)-mu*mu;
    float v = (acc-mu)*rsqrtf(var+EPSLN)*g_node[tid] + b_node[tid];
    node[bid*32+tid] = v;
    nodeS[tid] = v;
  }
  __syncthreads();
  if (tid<16){
    float acc = b0[tid];
    for (int k=0;k<32;k++) acc += nodeS[k]*W0[(32+k)*16+tid];
    m0bG[bid*16+tid] = acc;
  }

  // --- Phase 2: distances, exact stable top-k rank, compaction (tid<256, thread=j) ---
  const bool act = tid < 256;
  const int i = bid & 255;
  const int j = tid;
  float D = 0.f;
  if (act){
    const float cax = xyz[(bid*3+1)*3+0];
    const float cay = xyz[(bid*3+1)*3+1];
    const float caz = xyz[(bid*3+1)*3+2];
    const int jb = (b<<8)+j;
    float dx = xyz[(jb*3+1)*3+0]-cax;
    float dy = xyz[(jb*3+1)*3+1]-cay;
    float dz = xyz[(jb*3+1)*3+2]-caz;
    D = sqrtf(dx*dx+dy*dy+dz*dz) + (i==j ? 999.9f : 0.f);
  }
  __syncthreads();
  if (act) Dv[j] = D;
  __syncthreads();
  if (act){
    int rank = 0;
    for (int j2=0;j2<256;j2+=4){
      const float4 dv = *(const float4*)&Dv[j2];
      rank += (dv.x < D || (dv.x == D && (j2+0) < j)) ? 1 : 0;
      rank += (dv.y < D || (dv.y == D && (j2+1) < j)) ? 1 : 0;
      rank += (dv.z < D || (dv.z == D && (j2+2) < j)) ? 1 : 0;
      rank += (dv.w < D || (dv.w == D && (j2+3) < j)) ? 1 : 0;
    }
    int K = topk[0];
    if (K<=0 || K>256){
      float f = ((const float*)topk)[0];
      K = (f>=1.f && f<=256.f) ? (int)f : 64;
    }
    const int jb = (b<<8)+j;
    const int sep = abs(idxp[jb] - idxp[bid]);
    const bool m = (rank < K) || (i!=j && sep < KMINC);
    unsigned long long bal = __ballot(m);
    const int l6 = j & 63, wv = j >> 6;
    const int pre = __popcll(bal & ((1ull<<l6)-1ull));
    if (l6==0) wsum[wv] = __popcll(bal);
    __syncthreads();
    int off = 0;
    for (int w2=0;w2<wv;w2++) off += wsum[w2];
    if (m) jlist[bid*96 + off + pre] = j;
    if (j==0) cnt[bid] = wsum[0]+wsum[1]+wsum[2]+wsum[3];
  } else {
    __syncthreads();
  }
}

// ---------------- Kernel C: MFMA pipeline — one block per item, 5 waves = 5 M-tiles ----------------
// Wave w owns slots [16w,16w+16): stages 16 pair rows (f16, XOR-swizzled), then
// GEMM1 P[16x128]@Gw[128x32] (8 MFMA) -> LN-fold -> GEMM2 E@Gwa (2) -> fold+relu ->
// GEMM3 a@W0a + nd@W0c (2) -> state; GEMM4 a@Wc (1) -> offsets.
// Frag layouts: A row=lane&15,k=8*(lane>>4)+j; B col=lane&15 same k; C/D col=lane&15,
// row=4*(lane>>4)+reg (m89). LN stats land in exactly the lanes holding those rows.
__global__ __launch_bounds__(320) void k_main(
    const float* __restrict__ pair, const float* __restrict__ xyz,
    const float* __restrict__ node, const int* __restrict__ cnt,
    const int* __restrict__ jlist, const float* __restrict__ m0bG,
    const unsigned* __restrict__ packW, float* __restrict__ out)
{
  const int tid = threadIdx.x;
  const int w   = tid >> 6;         // wave 0..4
  const int L   = tid & 63;         // lane
  const int h   = L >> 5;           // half
  const int l32 = L & 31;           // lane-in-half
  const int q   = L >> 4;           // k-chunk / row-subgroup 0..3
  const int cl  = L & 15;           // col (B/D) or row (A)

  __shared__ alignas(16) unsigned char GwB[8192];
  __shared__ alignas(16) unsigned char GwaB[2048];
  __shared__ alignas(16) unsigned char W0aB[1024];
  __shared__ alignas(16) unsigned char W0cB[1024];
  __shared__ alignas(16) unsigned char WcB[1024];
  __shared__ float waDS[32], gwS[32], bwS[32], gwaS[32], bwaS[32];
  __shared__ float m0bS[16];
  __shared__ int   jbS[80];
  __shared__ alignas(16) unsigned char pnB[80*256];   // raw pair rows f16, swz (slot&7)<<4
  __shared__ alignas(16) unsigned char eB [80*64];    // raw edge f16, swz (slot&3)<<4
  __shared__ alignas(16) unsigned char aB [80*64];
  __shared__ alignas(16) unsigned char ndB[80*64];
  __shared__ float rsS[80], rmS[80];
  __shared__ float geoS[80][4];
  __shared__ float xjS[80][9];
  __shared__ float cS[80*12];
  __shared__ float pstS[NW][16];
  __shared__ float pofS[NW][9];

  const int item = blockIdx.x;
  const int b = item >> 8;
  const int n = cnt[item];

  // ---- prologue: weights + jbS + m0bS ----
  for (int i2=tid;i2<2048;i2+=320) ((unsigned*)GwB)[i2] = packW[i2];
  for (int i2=tid;i2<512; i2+=320) ((unsigned*)GwaB)[i2]= packW[2048+i2];
  if (tid<256){
    ((unsigned*)W0aB)[tid] = packW[2560+tid];
    ((unsigned*)W0cB)[tid] = packW[2816+tid];
    ((unsigned*)WcB)[tid]  = packW[3072+tid];
  }
  if (tid<160){
    const float* pf = (const float*)packW;
    float v = pf[3328+tid];
    if (tid<32) waDS[tid]=v;
    else if (tid<64) gwS[tid-32]=v;
    else if (tid<96) bwS[tid-64]=v;
    else if (tid<128) gwaS[tid-96]=v;
    else bwaS[tid-128]=v;
  }
  if (tid>=160 && tid<240) jbS[tid-160] = (b<<8) + (((tid-160)<n)? jlist[item*96 + (tid-160)] : 0);
  if (tid>=240 && tid<256) m0bS[tid-240] = m0bG[item*16 + (tid-240)];
  __syncthreads();

  const float cax = xyz[(item*3+1)*3+0];
  const float cay = xyz[(item*3+1)*3+1];
  const float caz = xyz[(item*3+1)*3+2];

  // ---- stage 16 rows (2 per iter, one per half) ----
  #pragma unroll
  for (int it=0; it<8; ++it){
    const int slot = 16*w + 2*it + h;
    const int jb = jbS[slot];
    const int jj = jb & 255;
    const float4 pv = *(const float4*)&pair[(((long)item*256 + jj)*128) + l32*4];
    const float nv = node[jb*32 + l32];
    if (l32<9) xjS[slot][l32] = xyz[(size_t)jb*9 + l32];
    // LN1 stats over the row (32 lanes of this half)
    float sm  = pv.x+pv.y+pv.z+pv.w;
    float sm2 = pv.x*pv.x+pv.y*pv.y+pv.z*pv.z+pv.w*pv.w;
    #pragma unroll
    for (int m=1;m<32;m<<=1){ sm += __shfl_xor(sm,m,64); sm2 += __shfl_xor(sm2,m,64); }
    const float mu = sm*(1.f/128.f);
    const float var = sm2*(1.f/128.f)-mu*mu;
    const float rs = rsqrtf(var+EPSLN);
    h4 o; o[0]=(_Float16)pv.x; o[1]=(_Float16)pv.y; o[2]=(_Float16)pv.z; o[3]=(_Float16)pv.w;
    *(h4*)&pnB[slot*256 + ((l32*8) ^ ((slot&7)<<4))] = o;
    *(_Float16*)&ndB[slot*64 + ((l32*2) ^ ((slot&3)<<4))] = (_Float16)nv;
    if (l32==0){
      rsS[slot]=rs; rmS[slot]=rs*mu;
      float jx = xyz[(size_t)jb*9+3]-cax;
      float jy = xyz[(size_t)jb*9+4]-cay;
      float jz = xyz[(size_t)jb*9+5]-caz;
      geoS[slot][0]=jx; geoS[slot][1]=jy; geoS[slot][2]=jz;
      geoS[slot][3]=sqrtf(jx*jx+jy*jy+jz*jz);
    }
  }

  const int sA = 16*w + cl;           // A-frag row-slot for this lane

  // ---- GEMM1: E = P @ Gw  (K=128 -> 4 steps, N=32 -> 2 tiles) ----
  f32x4 accE0 = {0.f,0.f,0.f,0.f}, accE1 = {0.f,0.f,0.f,0.f};
  #pragma unroll
  for (int s=0;s<4;++s){
    const h8 af = asH8(*(const uint4*)&pnB[sA*256 + ((s*64 + q*16) ^ ((sA&7)<<4))]);
    const h8 b0 = asH8(*(const uint4*)&GwB[cl*256 + ((s*64 + q*16) ^ ((cl&7)<<4))]);
    const h8 b1 = asH8(*(const uint4*)&GwB[(16+cl)*256 + ((s*64 + q*16) ^ (((16+cl)&7)<<4))]);
    accE0 = __builtin_amdgcn_mfma_f32_16x16x32_f16(af, b0, accE0, 0,0,0);
    accE1 = __builtin_amdgcn_mfma_f32_16x16x32_f16(af, b1, accE1, 0,0,0);
  }

  // ---- LN1 fold -> E raw; LN2 stats (per-row over 32 cols, in-lane) ----
  float mu2[4], rs2v[4];
  #pragma unroll
  for (int reg=0;reg<4;++reg){
    const int sr = 16*w + q*4 + reg;
    const float rs1 = rsS[sr], rm1 = rmS[sr];
    const float E0 = rs1*accE0[reg] - rm1*gwS[cl]    + bwS[cl];
    const float E1 = rs1*accE1[reg] - rm1*gwS[16+cl] + bwS[16+cl];
    float s1 = E0+E1, s2 = E0*E0+E1*E1;
    #pragma unroll
    for (int m=1;m<16;m<<=1){ s1 += __shfl_xor(s1,m,64); s2 += __shfl_xor(s2,m,64); }
    const float mu = s1*(1.f/32.f);
    const float var = s2*(1.f/32.f)-mu*mu;
    rs2v[reg] = rsqrtf(var+EPSLN);
    mu2[reg]  = mu;
    *(_Float16*)&eB[sr*64 + ((2*cl) ^ ((sr&3)<<4))]      = (_Float16)E0;
    *(_Float16*)&eB[sr*64 + ((2*(16+cl)) ^ ((sr&3)<<4))] = (_Float16)E1;
  }

  // ---- GEMM2: Eraw @ Gwa (K=32, N=32 -> 2 tiles) + fold2 + relu -> aB ----
  {
    const h8 eaf = asH8(*(const uint4*)&eB[sA*64 + ((q*16) ^ ((sA&3)<<4))]);
    const h8 gb0 = asH8(*(const uint4*)&GwaB[cl*64 + ((q*16) ^ ((cl&3)<<4))]);
    const h8 gb1 = asH8(*(const uint4*)&GwaB[(16+cl)*64 + ((q*16) ^ (((16+cl)&3)<<4))]);
    f32x4 z = {0.f,0.f,0.f,0.f};
    f32x4 accA0 = __builtin_amdgcn_mfma_f32_16x16x32_f16(eaf, gb0, z, 0,0,0);
    f32x4 accA1 = __builtin_amdgcn_mfma_f32_16x16x32_f16(eaf, gb1, z, 0,0,0);
    #pragma unroll
    for (int reg=0;reg<4;++reg){
      const int sr = 16*w + q*4 + reg;
      const float dist = geoS[sr][3];
      const float a0 = fmaxf(rs2v[reg]*accA0[reg] - rs2v[reg]*mu2[reg]*gwaS[cl]
                             + bwaS[cl] + dist*waDS[cl], 0.f);
      const float a1 = fmaxf(rs2v[reg]*accA1[reg] - rs2v[reg]*mu2[reg]*gwaS[16+cl]
                             + bwaS[16+cl] + dist*waDS[16+cl], 0.f);
      *(_Float16*)&aB[sr*64 + ((2*cl) ^ ((sr&3)<<4))]      = (_Float16)a0;
      *(_Float16*)&aB[sr*64 + ((2*(16+cl)) ^ ((sr&3)<<4))] = (_Float16)a1;
    }
  }

  // ---- GEMM3: m0 = relu(a@W0a + nd@W0c + m0b) -> state; GEMM4: c = a@Wc ----
  float stP = 0.f;
  {
    const h8 aaf = asH8(*(const uint4*)&aB[sA*64 + ((q*16) ^ ((sA&3)<<4))]);
    const h8 naf = asH8(*(const uint4*)&ndB[sA*64 + ((q*16) ^ ((sA&3)<<4))]);
    const h8 wa0 = asH8(*(const uint4*)&W0aB[cl*64 + ((q*16) ^ ((cl&3)<<4))]);
    const h8 wc0 = asH8(*(const uint4*)&W0cB[cl*64 + ((q*16) ^ ((cl&3)<<4))]);
    const h8 wcf = asH8(*(const uint4*)&WcB[cl*64 + ((q*16) ^ ((cl&3)<<4))]);
    f32x4 z = {0.f,0.f,0.f,0.f};
    f32x4 accM = __builtin_amdgcn_mfma_f32_16x16x32_f16(naf, wc0, z, 0,0,0);
    accM = __builtin_amdgcn_mfma_f32_16x16x32_f16(aaf, wa0, accM, 0,0,0);
    f32x4 accC = __builtin_amdgcn_mfma_f32_16x16x32_f16(aaf, wcf, z, 0,0,0);
    #pragma unroll
    for (int reg=0;reg<4;++reg){
      const int sr = 16*w + q*4 + reg;
      if (sr < n) stP += fmaxf(accM[reg] + m0bS[cl], 0.f);
      if (cl < 12) cS[sr*12 + cl] = accC[reg];
    }
  }
  stP += __shfl_xor(stP, 16, 64);
  stP += __shfl_xor(stP, 32, 64);
  if (L < 16) pstS[w][L] = stP;

  // ---- offsets: each half processes its 8 slots on lanes t<9 ----
  float ofP = 0.f;
  if (l32 < 9){
    const int o = l32/3, x = l32 - o*3;
    #pragma unroll
    for (int jc=0;jc<8;++jc){
      const int slot = 16*w + h*8 + jc;
      if (slot < n){
        const float dj = geoS[slot][3];
        const float dh = geoS[slot][x]/(dj+1e-8f);
        const float* cr = &cS[slot*12];
        float val = cr[o]*dh;
        const float caxj = xjS[slot][3+x];
        #pragma unroll
        for (int c2=0;c2<3;c2++) val += cr[3+o*3+c2]*(xjS[slot][c2*3+x]-caxj);
        ofP += val;
      }
    }
  }
  ofP += __shfl_xor(ofP, 32, 64);
  if (L < 9) pofS[w][L] = ofP;
  __syncthreads();

  // ---- in-block finisher (wave 0, fixed order -> deterministic) ----
  if (tid < 64){
    const float invd = 1.f/fmaxf((float)n,1.f);
    float sst=0.f, sof=0.f;
    #pragma unroll
    for (int k2=0;k2<NW;k2++){
      if (L<16) sst += pstS[k2][L];
      if (L<9)  sof += pofS[k2][L];
    }
    if (L<16) out[4608 + item*16 + L] = sst*invd;        // state
    const float off = sof*invd;
    const int x = L - (L/3)*3;
    const float offca = __shfl(off, 3+x, 64);            // off[3+x]
    if (L<9){
      const float cac = xyz[(item*3+1)*3 + x];
      const float CA = cac + offca;
      const int o = L/3;
      out[item*9 + L] = (o==1)? CA : (CA + off);         // xyz_new
    }
  }
}

extern "C" void kernel_launch(void* const* d_in, const int* in_sizes, int n_in,
                              void* d_out, int out_size, void* d_ws, size_t ws_size,
                              hipStream_t stream)
{
  const float* msa     = (const float*)d_in[0];
  const float* pair    = (const float*)d_in[1];
  const float* xyz     = (const float*)d_in[2];
  const float* seq1hot = (const float*)d_in[3];
  const float* g_msa   = (const float*)d_in[4];
  const float* b_msa   = (const float*)d_in[5];
  const float* g_pair  = (const float*)d_in[6];
  const float* b_pair  = (const float*)d_in[7];
  const float* Wq      = (const float*)d_in[8];
  const float* bq      = (const float*)d_in[9];
  const float* Wk      = (const float*)d_in[10];
  const float* bk      = (const float*)d_in[11];
  const float* Wx      = (const float*)d_in[12];
  const float* bx      = (const float*)d_in[13];
  const float* g_node  = (const float*)d_in[14];
  const float* b_node  = (const float*)d_in[15];
  const float* We      = (const float*)d_in[16];
  const float* be      = (const float*)d_in[17];
  const float* g_edge  = (const float*)d_in[18];
  const float* b_edge  = (const float*)d_in[19];
  const float* Wa      = (const float*)d_in[20];
  const float* ba      = (const float*)d_in[21];
  const float* W0      = (const float*)d_in[22];
  const float* b0      = (const float*)d_in[23];
  const float* Wc1     = (const float*)d_in[24];
  const float* Wc2     = (const float*)d_in[25];
  const int*   idx     = (const int*)d_in[26];
  const int*   topk    = (const int*)d_in[27];
  float* out = (float*)d_out;

  float* wsf = (float*)d_ws;
  float*    node  = wsf + WS_NODE;
  int*      cnt   = (int*)(wsf + WS_CNT);
  int*      jlist = (int*)(wsf + WS_JLIST);
  float*    m0bG  = wsf + WS_M0B;
  unsigned* packW = (unsigned*)(wsf + WS_PACKW);

  k_prep<<<512, 512, 0, stream>>>(msa, seq1hot, xyz, idx, topk, g_msa, b_msa,
                                  g_pair, b_pair, Wq, bq, Wk, bk, Wx, bx,
                                  g_node, b_node, We, be, g_edge, b_edge,
                                  Wa, ba, W0, b0, Wc1, Wc2,
                                  node, cnt, jlist, m0bG, packW);
  k_main<<<512, 320, 0, stream>>>(pair, xyz, node, cnt, jlist, m0bG,
                                  packW, out);
}